// Round 2
// baseline (2459.216 us; speedup 1.0000x reference)
//
#include <hip/hip_runtime.h>
#include <hip/hip_bf16.h>

typedef unsigned short u16;

#define BM 64
#define BN 64
#define BK 16

__device__ __forceinline__ float us2f(u16 u) {
    union { unsigned int i; float f; } x;
    x.i = ((unsigned int)u) << 16;
    return x.f;
}

__device__ __forceinline__ u16 f2us(float f) {
    union { float f; unsigned int i; } x; x.f = f;
    unsigned int lsb = (x.i >> 16) & 1u;
    x.i += 0x7FFFu + lsb;            // round-to-nearest-even
    return (u16)(x.i >> 16);
}

// 16B vector load -> 4 floats, overloaded on source dtype
__device__ __forceinline__ float4 ld4(const float* p) {
    return *reinterpret_cast<const float4*>(p);
}
__device__ __forceinline__ float4 ld4(const u16* p) {
    ushort4 v = *reinterpret_cast<const ushort4*>(p);
    return make_float4(us2f(v.x), us2f(v.y), us2f(v.z), us2f(v.w));
}
__device__ __forceinline__ void st4(float* p, float4 v) {
    *reinterpret_cast<float4*>(p) = v;
}
__device__ __forceinline__ void st4(u16* p, float4 v) {
    ushort4 o;
    o.x = f2us(v.x); o.y = f2us(v.y); o.z = f2us(v.z); o.w = f2us(v.w);
    *reinterpret_cast<ushort4*>(p) = o;
}

// ---------------------------------------------------------------------------
// Generic tiled NN GEMM: C[m,n] = sum_k A[m,k]*B[k,n] + bias[n], fp32 accum.
// TA/TB/TC in {float, u16}. Optional fused interleaved RoPE epilogue
// (ropeHD>0). Batched via blockIdx.z with (outer, inner) offset decomposition.
// Requires: M%64==0, N%64==0, K%16==0, leading dims / offsets %4==0.
// ---------------------------------------------------------------------------
template <typename TA, typename TB, typename TC>
__global__ __launch_bounds__(256)
void gemm_nn(const TA* __restrict__ A, const TB* __restrict__ B,
             const float* __restrict__ bias, TC* __restrict__ C,
             int M, int N, int K, int lda, int ldb, int ldc,
             long sAo, long sAi, long sBo, long sBi, long sCo, long sCi,
             int innerCnt, int ropeHD, int Slen)
{
    __shared__ float As[BK][BM];   // [k][m]
    __shared__ float Bs[BK][BN];   // [k][n]

    int z  = blockIdx.z;
    int zo = z / innerCnt, zi = z - zo * innerCnt;
    A += zo * sAo + zi * sAi;
    B += zo * sBo + zi * sBi;
    C += zo * sCo + zi * sCi;

    int tid = threadIdx.x;
    int tx = tid & 15;          // n-direction (4 cols each)
    int ty = tid >> 4;          // m-direction (4 rows each)
    int m0 = blockIdx.y * BM;
    int n0 = blockIdx.x * BN;

    int arow = tid >> 2;            // 0..63 (m)
    int acol = (tid & 3) << 2;      // 0,4,8,12 (k)
    int brow = tid >> 4;            // 0..15 (k)
    int bcol = (tid & 15) << 2;     // 0..60 (n)

    float acc[4][4] = {{0.f}};

    for (int k0 = 0; k0 < K; k0 += BK) {
        float4 av = ld4(A + (long)(m0 + arow) * lda + (k0 + acol));
        float4 bv = ld4(B + (long)(k0 + brow) * ldb + (n0 + bcol));
        As[acol + 0][arow] = av.x;
        As[acol + 1][arow] = av.y;
        As[acol + 2][arow] = av.z;
        As[acol + 3][arow] = av.w;
        *reinterpret_cast<float4*>(&Bs[brow][bcol]) = bv;
        __syncthreads();
#pragma unroll
        for (int kk = 0; kk < BK; ++kk) {
            float4 a4 = *reinterpret_cast<const float4*>(&As[kk][ty << 2]);
            float4 b4 = *reinterpret_cast<const float4*>(&Bs[kk][tx << 2]);
            float a[4] = {a4.x, a4.y, a4.z, a4.w};
            float b[4] = {b4.x, b4.y, b4.z, b4.w};
#pragma unroll
            for (int i = 0; i < 4; ++i)
#pragma unroll
                for (int j = 0; j < 4; ++j)
                    acc[i][j] = fmaf(a[i], b[j], acc[i][j]);
        }
        __syncthreads();
    }

    if (bias) {
#pragma unroll
        for (int j = 0; j < 4; ++j) {
            float bv = bias[n0 + (tx << 2) + j];
#pragma unroll
            for (int i = 0; i < 4; ++i) acc[i][j] += bv;
        }
    }

    if (ropeHD > 0) {
        // interleaved rotation over pairs (r, r+1) along n within each head
#pragma unroll
        for (int j = 0; j < 4; j += 2) {
            int n = n0 + (tx << 2) + j;     // even
            int r = n % ropeHD;             // even
            float freq = expf(-9.2103403719761836f * (float)r / (float)ropeHD);
#pragma unroll
            for (int i = 0; i < 4; ++i) {
                int m = m0 + (ty << 2) + i;
                float pos = (float)(m % Slen);
                float th = pos * freq;
                float sn = sinf(th), cs = cosf(th);
                float q1 = acc[i][j], q2 = acc[i][j + 1];
                acc[i][j]     = q1 * cs - q2 * sn;
                acc[i][j + 1] = q2 * cs + q1 * sn;
            }
        }
    }

#pragma unroll
    for (int i = 0; i < 4; ++i) {
        long crow = (long)(m0 + (ty << 2) + i) * ldc + n0 + (tx << 2);
        st4(C + crow, make_float4(acc[i][0], acc[i][1], acc[i][2], acc[i][3]));
    }
}

// ---------------------------------------------------------------------------
// Scores: attn[z=(b-b0)*16+h][m][n] = (q_c.k_c (K=128) + q_r.k_r (K=512))/scale
// q_c/k_c layout [B*S, H*128] (stride 2048), q_r [B*S, H*512] (stride 8192),
// k_r [B*S, 512]. NT product (both operands K-contiguous). All bf16.
// ---------------------------------------------------------------------------
__global__ __launch_bounds__(256)
void scores_nt(const u16* __restrict__ qc, const u16* __restrict__ qr,
               const u16* __restrict__ kc, const u16* __restrict__ kr,
               u16* __restrict__ attn, int b0)
{
    __shared__ float As[BK][BM];
    __shared__ float Bs[BK][BN];

    int z = blockIdx.z;          // 0..63 (chunk-local)
    int b = b0 + (z >> 4), h = z & 15;

    const u16* qcb = qc + ((long)b * 512) * 2048 + h * 128;
    const u16* qrb = qr + ((long)b * 512) * 8192 + h * 512;
    const u16* kcb = kc + ((long)b * 512) * 2048 + h * 128;
    const u16* krb = kr + ((long)b * 512) * 512;
    u16* Cb = attn + (long)z * 512 * 512;

    int tid = threadIdx.x;
    int tx = tid & 15, ty = tid >> 4;
    int m0 = blockIdx.y * BM, n0 = blockIdx.x * BN;

    int arow = tid >> 2;            // 0..63 (row within tile)
    int acol = (tid & 3) << 2;      // k offset

    float acc[4][4] = {{0.f}};

    for (int kt = 0; kt < 40; ++kt) {
        const u16 *Ab, *Bb;
        int la, lb, kloc;
        if (kt < 8) { Ab = qcb; Bb = kcb; la = 2048; lb = 2048; kloc = kt * 16; }
        else        { Ab = qrb; Bb = krb; la = 8192; lb = 512;  kloc = (kt - 8) * 16; }
        float4 av = ld4(Ab + (long)(m0 + arow) * la + kloc + acol);
        float4 bv = ld4(Bb + (long)(n0 + arow) * lb + kloc + acol);
        As[acol + 0][arow] = av.x;
        As[acol + 1][arow] = av.y;
        As[acol + 2][arow] = av.z;
        As[acol + 3][arow] = av.w;
        Bs[acol + 0][arow] = bv.x;
        Bs[acol + 1][arow] = bv.y;
        Bs[acol + 2][arow] = bv.z;
        Bs[acol + 3][arow] = bv.w;
        __syncthreads();
#pragma unroll
        for (int kk = 0; kk < BK; ++kk) {
            float4 a4 = *reinterpret_cast<const float4*>(&As[kk][ty << 2]);
            float4 b4 = *reinterpret_cast<const float4*>(&Bs[kk][tx << 2]);
            float a[4] = {a4.x, a4.y, a4.z, a4.w};
            float b[4] = {b4.x, b4.y, b4.z, b4.w};
#pragma unroll
            for (int i = 0; i < 4; ++i)
#pragma unroll
                for (int j = 0; j < 4; ++j)
                    acc[i][j] = fmaf(a[i], b[j], acc[i][j]);
        }
        __syncthreads();
    }

    const float invScale = 1.0f / 33.941125496954285f;  // 1/(sqrt(128)+sqrt(512))
#pragma unroll
    for (int i = 0; i < 4; ++i) {
        long crow = (long)(m0 + (ty << 2) + i) * 512 + n0 + (tx << 2);
        st4(Cb + crow, make_float4(acc[i][0] * invScale, acc[i][1] * invScale,
                                   acc[i][2] * invScale, acc[i][3] * invScale));
    }
}

// ---------------------------------------------------------------------------
// Row softmax in-place over rows of 512 (one wave per row, 4 rows/block)
// ---------------------------------------------------------------------------
__global__ __launch_bounds__(256)
void softmax_rows(u16* __restrict__ attn)
{
    int row  = blockIdx.x * 4 + (threadIdx.x >> 6);
    int lane = threadIdx.x & 63;
    u16* p = attn + (long)row * 512;

    float v[8];
#pragma unroll
    for (int i = 0; i < 8; ++i) v[i] = us2f(p[lane + (i << 6)]);

    float mx = v[0];
#pragma unroll
    for (int i = 1; i < 8; ++i) mx = fmaxf(mx, v[i]);
#pragma unroll
    for (int off = 32; off >= 1; off >>= 1)
        mx = fmaxf(mx, __shfl_xor(mx, off, 64));

    float e[8], s = 0.f;
#pragma unroll
    for (int i = 0; i < 8; ++i) { e[i] = expf(v[i] - mx); s += e[i]; }
#pragma unroll
    for (int off = 32; off >= 1; off >>= 1)
        s += __shfl_xor(s, off, 64);

    float inv = 1.0f / s;
#pragma unroll
    for (int i = 0; i < 8; ++i) p[lane + (i << 6)] = f2us(e[i] * inv);
}

// ---------------------------------------------------------------------------
extern "C" void kernel_launch(void* const* d_in, const int* in_sizes, int n_in,
                              void* d_out, int out_size, void* d_ws, size_t ws_size,
                              hipStream_t stream)
{
    (void)in_sizes; (void)n_in; (void)out_size; (void)ws_size;

    // All harness inputs are fp32 (reference dtype); output fp32.
    const float* X    = (const float*)d_in[0];
    const float* Wdq  = (const float*)d_in[1];  const float* bdq  = (const float*)d_in[2];
    const float* Wdkv = (const float*)d_in[3];  const float* bdkv = (const float*)d_in[4];
    const float* Wuq  = (const float*)d_in[5];  const float* buq  = (const float*)d_in[6];
    const float* Wuk  = (const float*)d_in[7];  const float* buk  = (const float*)d_in[8];
    const float* Wuv  = (const float*)d_in[9];  const float* buv  = (const float*)d_in[10];
    const float* Wqr  = (const float*)d_in[11]; const float* bqr  = (const float*)d_in[12];
    const float* Wkr  = (const float*)d_in[13]; const float* bkr  = (const float*)d_in[14];
    const float* Wfc  = (const float*)d_in[15]; const float* bfc  = (const float*)d_in[16];
    float* out = (float*)d_out;

    // workspace layout (bf16 intermediates), peak ~174 MB
    u16* ws = (u16*)d_ws;
    u16* c_q  = ws;  ws += 4096l * 512;
    u16* c_kv = ws;  ws += 4096l * 512;
    u16* q_c  = ws;  ws += 4096l * 2048;   // [B*S, H*128]
    u16* k_c  = ws;  ws += 4096l * 2048;
    u16* v_c  = ws;  ws += 4096l * 2048;
    u16* q_r  = ws;  ws += 4096l * 8192;   // [B*S, H*512], rope applied
    u16* k_r  = ws;  ws += 4096l * 512;    // [B*S, 512], rope applied
    u16* attn = ws;  ws += 64l * 512 * 512;  // half-batch chunk (b0..b0+3)
    u16* o    = ws;  ws += 4096l * 2048;   // [B*S, H*128]

    dim3 blk(256, 1, 1);

    // down projections: fp32 A/B -> bf16 C
    gemm_nn<float, float, u16><<<dim3(512 / BN, 4096 / BM, 1), blk, 0, stream>>>(
        X, Wdq, bdq, c_q, 4096, 512, 2048, 2048, 512, 512, 0,0,0,0,0,0, 1, 0, 512);
    gemm_nn<float, float, u16><<<dim3(512 / BN, 4096 / BM, 1), blk, 0, stream>>>(
        X, Wdkv, bdkv, c_kv, 4096, 512, 2048, 2048, 512, 512, 0,0,0,0,0,0, 1, 0, 512);

    // up projections (content): bf16 A, fp32 B -> bf16 C
    gemm_nn<u16, float, u16><<<dim3(2048 / BN, 4096 / BM, 1), blk, 0, stream>>>(
        c_q, Wuq, buq, q_c, 4096, 2048, 512, 512, 2048, 2048, 0,0,0,0,0,0, 1, 0, 512);
    gemm_nn<u16, float, u16><<<dim3(2048 / BN, 4096 / BM, 1), blk, 0, stream>>>(
        c_kv, Wuk, buk, k_c, 4096, 2048, 512, 512, 2048, 2048, 0,0,0,0,0,0, 1, 0, 512);
    gemm_nn<u16, float, u16><<<dim3(2048 / BN, 4096 / BM, 1), blk, 0, stream>>>(
        c_kv, Wuv, buv, v_c, 4096, 2048, 512, 512, 2048, 2048, 0,0,0,0,0,0, 1, 0, 512);

    // rope branches (fused rope epilogue, head_dim=512)
    gemm_nn<u16, float, u16><<<dim3(8192 / BN, 4096 / BM, 1), blk, 0, stream>>>(
        c_q, Wqr, bqr, q_r, 4096, 8192, 512, 512, 8192, 8192, 0,0,0,0,0,0, 1, 512, 512);
    gemm_nn<float, float, u16><<<dim3(512 / BN, 4096 / BM, 1), blk, 0, stream>>>(
        X, Wkr, bkr, k_r, 4096, 512, 2048, 2048, 512, 512, 0,0,0,0,0,0, 1, 512, 512);

    // attention in two batch-halves to shrink the attn scratch
    for (int half = 0; half < 2; ++half) {
        int b0 = half * 4;
        scores_nt<<<dim3(512 / BN, 512 / BM, 64), blk, 0, stream>>>(
            q_c, q_r, k_c, k_r, attn, b0);
        softmax_rows<<<dim3(64 * 512 / 4, 1, 1), blk, 0, stream>>>(attn);
        // o[b,s,h*128+d] = attn[b,h] @ v_c[b,h]  (batched over z = (b-b0)*16+h)
        gemm_nn<u16, u16, u16><<<dim3(128 / BN, 512 / BM, 64), blk, 0, stream>>>(
            attn, v_c + (long)b0 * 512 * 2048, nullptr, o + (long)b0 * 512 * 2048,
            512, 128, 512, 512, 2048, 2048,
            (long)16 * 512 * 512, (long)512 * 512,   // A: b-stride, h-stride
            (long)512 * 2048,     128,               // B: b-stride, h-stride
            (long)512 * 2048,     128,               // C: b-stride, h-stride
            16, 0, 512);
    }

    // final projection: bf16 A, fp32 B -> fp32 out
    gemm_nn<u16, float, float><<<dim3(2048 / BN, 4096 / BM, 1), blk, 0, stream>>>(
        o, Wfc, bfc, out, 4096, 2048, 2048, 2048, 2048, 2048, 0,0,0,0,0,0, 1, 0, 512);
}

// Round 3
// 772.304 us; speedup vs baseline: 3.1843x; 3.1843x over previous
//
#include <hip/hip_runtime.h>
#include <hip/hip_bf16.h>
#include <stdint.h>

typedef unsigned short u16;
typedef short bf16x8 __attribute__((ext_vector_type(8)));
typedef float f32x4 __attribute__((ext_vector_type(4)));

__device__ __forceinline__ float us2f(u16 u) {
    union { unsigned int i; float f; } x;
    x.i = ((unsigned int)u) << 16;
    return x.f;
}

__device__ __forceinline__ u16 f2us(float f) {
    union { float f; unsigned int i; } x; x.f = f;
    unsigned int lsb = (x.i >> 16) & 1u;
    x.i += 0x7FFFu + lsb;            // round-to-nearest-even
    return (u16)(x.i >> 16);
}

// async global->LDS, 16B per lane. LDS dest = wave-uniform base + lane*16.
__device__ __forceinline__ void gl_lds16(const u16* g, u16* l) {
    __builtin_amdgcn_global_load_lds(
        (const __attribute__((address_space(1))) void*)(uintptr_t)(const void*)g,
        (__attribute__((address_space(3))) void*)(uintptr_t)(void*)l,
        16, 0, 0);
}

#define FLAG_ROPE   1
#define FLAG_SCALE  2
#define FLAG_TRANSC 4
#define FLAG_F32OUT 8

struct GArgs {
    const u16 *A0, *A1, *B0, *B1;
    long sA0o, sA0i, sA1o, sA1i, sB0o, sB0i, sB1o, sB1i;
    int ldA0, ldA1, ldB0, ldB1;
    int K0, K1;
    const float* bias;
    void* C; long sCo, sCi; int ldc;
    int innerCnt;
    int flags;
    float scale;
};

// ---------------------------------------------------------------------------
// NT MFMA GEMM: C[m,n] = sum_k A[m,k]*Bt[n,k] (+ optional 2nd K-segment)
// 128x128 tile, BK=32, 256 threads = 4 waves in 2x2, each wave 64x64.
// bf16 in (both operands [rows][K] K-major), fp32 accum, bf16/f32 out.
// Requires M%128==0, N%128==0, K0%32==0, K1%32==0, lds*2B %16==0.
// ---------------------------------------------------------------------------
__global__ __launch_bounds__(256)
void gemm_mfma(GArgs g)
{
    __shared__ u16 As[128 * 32];
    __shared__ u16 Bs[128 * 32];

    const int t    = threadIdx.x;
    const int lane = t & 63;
    const int w    = t >> 6;
    const int wm   = w >> 1, wn = w & 1;
    const int m0   = blockIdx.y * 128;
    const int n0   = blockIdx.x * 128;

    const int z  = blockIdx.z;
    const int zo = z / g.innerCnt, zi = z - zo * g.innerCnt;
    const u16* A0 = g.A0 + zo * g.sA0o + zi * g.sA0i;
    const u16* B0 = g.B0 + zo * g.sB0o + zi * g.sB0i;
    const u16* A1 = g.A1 ? g.A1 + zo * g.sA1o + zi * g.sA1i : (const u16*)0;
    const u16* B1 = g.B1 ? g.B1 + zo * g.sB1o + zi * g.sB1i : (const u16*)0;

    // staging: thread t handles LDS 16B-chunk t (row sr, slot sp) per half-tile.
    const int sr = t >> 2;                       // 0..63 row within half
    const int sp = t & 3;                        // LDS slot in row
    const int sc = (sp - ((sr >> 1) & 3)) & 3;   // swizzled global chunk
    u16* aDst = As + t * 8;                      // *16B = *8 elems
    u16* bDst = Bs + t * 8;

    // fragment read: lane lr=row-in-16, jj=k-chunk; slot = (jj + (row>>1)) & 3
    const int lr  = lane & 15;
    const int jj  = lane >> 4;
    const int pos = (jj + ((lr >> 1) & 3)) & 3;

    f32x4 acc[4][4];
#pragma unroll
    for (int i = 0; i < 4; ++i)
#pragma unroll
        for (int j = 0; j < 4; ++j)
            acc[i][j] = (f32x4){0.f, 0.f, 0.f, 0.f};

    const int nk0 = g.K0 >> 5, nk1 = g.K1 >> 5;
    for (int kt = 0; kt < nk0 + nk1; ++kt) {
        const u16 *pa, *pb; int la, lb, kloc;
        if (kt < nk0) { pa = A0; pb = B0; la = g.ldA0; lb = g.ldB0; kloc = kt << 5; }
        else          { pa = A1; pb = B1; la = g.ldA1; lb = g.ldB1; kloc = (kt - nk0) << 5; }

        gl_lds16(pa + (long)(m0 + sr)      * la + kloc + sc * 8, aDst);
        gl_lds16(pa + (long)(m0 + 64 + sr) * la + kloc + sc * 8, aDst + 2048);
        gl_lds16(pb + (long)(n0 + sr)      * lb + kloc + sc * 8, bDst);
        gl_lds16(pb + (long)(n0 + 64 + sr) * lb + kloc + sc * 8, bDst + 2048);
        __syncthreads();   // emits s_waitcnt vmcnt(0) + s_barrier

        bf16x8 af[4], bfr[4];
#pragma unroll
        for (int mi = 0; mi < 4; ++mi)
            af[mi] = *(const bf16x8*)&As[(wm * 64 + mi * 16 + lr) * 32 + pos * 8];
#pragma unroll
        for (int ni = 0; ni < 4; ++ni)
            bfr[ni] = *(const bf16x8*)&Bs[(wn * 64 + ni * 16 + lr) * 32 + pos * 8];
#pragma unroll
        for (int mi = 0; mi < 4; ++mi)
#pragma unroll
            for (int ni = 0; ni < 4; ++ni)
                acc[mi][ni] = __builtin_amdgcn_mfma_f32_16x16x32_bf16(
                    af[mi], bfr[ni], acc[mi][ni], 0, 0, 0);
        __syncthreads();
    }

    // epilogue. C/D layout: col = lane&15, row = (lane>>4)*4 + reg.
    const int esz = (g.flags & FLAG_F32OUT) ? 4 : 2;
    char* Cb = (char*)g.C + (zo * g.sCo + zi * g.sCi) * esz;
    const int eCol0   = n0 + wn * 64 + lr;
    const int eRow0   = m0 + wm * 64 + jj * 4;
    const int flags   = g.flags;
    const bool oddc   = lane & 1;

    float biasv[4];
    if (g.bias) {
#pragma unroll
        for (int ni = 0; ni < 4; ++ni) biasv[ni] = g.bias[eCol0 + ni * 16];
    }

#pragma unroll
    for (int mi = 0; mi < 4; ++mi) {
#pragma unroll
        for (int ni = 0; ni < 4; ++ni) {
            f32x4 v = acc[mi][ni];
            if (g.bias) {
                float bv = biasv[ni];
                v[0] += bv; v[1] += bv; v[2] += bv; v[3] += bv;
            }
            if (flags & FLAG_SCALE) {
                v[0] *= g.scale; v[1] *= g.scale; v[2] *= g.scale; v[3] *= g.scale;
            }
            if (flags & FLAG_ROPE) {
                int col = eCol0 + ni * 16;
                int rp  = (col & 511) & ~1;
                float freq = expf(-9.2103403719761836f * (float)rp * (1.0f / 512.0f));
#pragma unroll
                for (int i = 0; i < 4; ++i) {
                    int row = eRow0 + mi * 16 + i;
                    float th = (float)(row & 511) * freq;
                    float sn = sinf(th), cs = cosf(th);
                    float other = __shfl_xor(v[i], 1, 64);
                    v[i] = oddc ? (v[i] * cs + other * sn)
                                : (v[i] * cs - other * sn);
                }
            }
            int rowb = eRow0 + mi * 16;
            int col  = eCol0 + ni * 16;
            if (flags & FLAG_TRANSC) {
                u16* cp = (u16*)Cb + (long)col * g.ldc + rowb;
                ushort4 o4;
                o4.x = f2us(v[0]); o4.y = f2us(v[1]);
                o4.z = f2us(v[2]); o4.w = f2us(v[3]);
                *(ushort4*)cp = o4;
            } else if (flags & FLAG_F32OUT) {
                float* cp = (float*)Cb;
#pragma unroll
                for (int i = 0; i < 4; ++i)
                    cp[(long)(rowb + i) * g.ldc + col] = v[i];
            } else {
                u16* cp = (u16*)Cb;
#pragma unroll
                for (int i = 0; i < 4; ++i)
                    cp[(long)(rowb + i) * g.ldc + col] = f2us(v[i]);
            }
        }
    }
}

// ---------------------------------------------------------------------------
// fp32 -> bf16 elementwise (vectorized x4)
// ---------------------------------------------------------------------------
__global__ __launch_bounds__(256)
void conv_f32_bf16(const float* __restrict__ in, u16* __restrict__ out)
{
    int i = blockIdx.x * 256 + threadIdx.x;
    float4 v = ((const float4*)in)[i];
    ushort4 o;
    o.x = f2us(v.x); o.y = f2us(v.y); o.z = f2us(v.z); o.w = f2us(v.w);
    ((ushort4*)out)[i] = o;
}

// ---------------------------------------------------------------------------
// fp32 [K][N] -> bf16 [N][K] transpose-convert, 32x32 LDS tile
// ---------------------------------------------------------------------------
__global__ __launch_bounds__(256)
void tconv(const float* __restrict__ in, u16* __restrict__ out, int K, int N)
{
    __shared__ float tile[32][33];
    int n0 = blockIdx.x * 32, k0 = blockIdx.y * 32;
    int c = threadIdx.x & 31, r0 = threadIdx.x >> 5;
#pragma unroll
    for (int j = 0; j < 4; ++j) {
        int r = r0 + j * 8;
        tile[r][c] = in[(long)(k0 + r) * N + n0 + c];
    }
    __syncthreads();
#pragma unroll
    for (int j = 0; j < 4; ++j) {
        int r = r0 + j * 8;
        out[(long)(n0 + r) * K + k0 + c] = f2us(tile[c][r]);
    }
}

// ---------------------------------------------------------------------------
// Row softmax in-place over rows of 512 (one wave per row, 4 rows/block)
// ---------------------------------------------------------------------------
__global__ __launch_bounds__(256)
void softmax_rows(u16* __restrict__ attn)
{
    int row  = blockIdx.x * 4 + (threadIdx.x >> 6);
    int lane = threadIdx.x & 63;
    u16* p = attn + (long)row * 512;

    float v[8];
#pragma unroll
    for (int i = 0; i < 8; ++i) v[i] = us2f(p[lane + (i << 6)]);

    float mx = v[0];
#pragma unroll
    for (int i = 1; i < 8; ++i) mx = fmaxf(mx, v[i]);
#pragma unroll
    for (int off = 32; off >= 1; off >>= 1)
        mx = fmaxf(mx, __shfl_xor(mx, off, 64));

    float e[8], s = 0.f;
#pragma unroll
    for (int i = 0; i < 8; ++i) { e[i] = expf(v[i] - mx); s += e[i]; }
#pragma unroll
    for (int off = 32; off >= 1; off >>= 1)
        s += __shfl_xor(s, off, 64);

    float inv = 1.0f / s;
#pragma unroll
    for (int i = 0; i < 8; ++i) p[lane + (i << 6)] = f2us(e[i] * inv);
}

// ---------------------------------------------------------------------------
extern "C" void kernel_launch(void* const* d_in, const int* in_sizes, int n_in,
                              void* d_out, int out_size, void* d_ws, size_t ws_size,
                              hipStream_t stream)
{
    (void)in_sizes; (void)n_in; (void)out_size; (void)ws_size;

    const float* X    = (const float*)d_in[0];
    const float* Wdq  = (const float*)d_in[1];  const float* bdq  = (const float*)d_in[2];
    const float* Wdkv = (const float*)d_in[3];  const float* bdkv = (const float*)d_in[4];
    const float* Wuq  = (const float*)d_in[5];  const float* buq  = (const float*)d_in[6];
    const float* Wuk  = (const float*)d_in[7];  const float* buk  = (const float*)d_in[8];
    const float* Wuv  = (const float*)d_in[9];  const float* buv  = (const float*)d_in[10];
    const float* Wqr  = (const float*)d_in[11]; const float* bqr  = (const float*)d_in[12];
    const float* Wkr  = (const float*)d_in[13]; const float* bkr  = (const float*)d_in[14];
    const float* Wfc  = (const float*)d_in[15]; const float* bfc  = (const float*)d_in[16];
    float* out = (float*)d_out;

    // workspace (u16 elems). region0 (Xb + all Wt except Wfc) is reused as attn.
    u16* ws = (u16*)d_ws;
    u16* Xb     = ws;                 // 4096x2048            (8M)
    u16* Wdq_t  = Xb     + 8388608;   // [512][2048]          (1M)
    u16* Wdkv_t = Wdq_t  + 1048576;   // [512][2048]          (1M)
    u16* Wuq_t  = Wdkv_t + 1048576;   // [2048][512]          (1M)
    u16* Wuk_t  = Wuq_t  + 1048576;   // [2048][512]          (1M)
    u16* Wuv_t  = Wuk_t  + 1048576;   // [2048][512]          (1M)
    u16* Wqr_t  = Wuv_t  + 1048576;   // [8192][512]          (4M)
    u16* Wkr_t  = Wqr_t  + 4194304;   // [512][2048]          (1M)
    u16* attn   = Xb;                 // 64x512x512 = 16M  (aliases region0: 18M)
    u16* Wfc_t  = Wkr_t  + 1048576;   // [2048][2048]         (4M)
    u16* c_q    = Wfc_t  + 4194304;   // [4096][512]          (2M)
    u16* c_kv   = c_q    + 2097152;   // [4096][512]          (2M)
    u16* q_c    = c_kv   + 2097152;   // [4096][2048]         (8M)
    u16* k_c    = q_c    + 8388608;   // [4096][2048]         (8M)
    u16* v_t    = k_c    + 8388608;   // [2048][4096] (V^T)   (8M)
    u16* q_r    = v_t    + 8388608;   // [4096][8192]         (32M)
    u16* k_r    = q_r    + 33554432;  // [4096][512]          (2M)
    u16* o      = k_r    + 2097152;   // [4096][2048]         (8M)  total 92M elems = 184MB

    dim3 blk(256, 1, 1);

    // ---- converts ----
    conv_f32_bf16<<<8192, blk, 0, stream>>>(X, Xb);   // 8M elems / 4 / 256
    tconv<<<dim3(512 / 32, 2048 / 32), blk, 0, stream>>>(Wdq,  Wdq_t,  2048, 512);
    tconv<<<dim3(512 / 32, 2048 / 32), blk, 0, stream>>>(Wdkv, Wdkv_t, 2048, 512);
    tconv<<<dim3(2048 / 32, 512 / 32), blk, 0, stream>>>(Wuq,  Wuq_t,  512, 2048);
    tconv<<<dim3(2048 / 32, 512 / 32), blk, 0, stream>>>(Wuk,  Wuk_t,  512, 2048);
    tconv<<<dim3(2048 / 32, 512 / 32), blk, 0, stream>>>(Wuv,  Wuv_t,  512, 2048);
    tconv<<<dim3(8192 / 32, 512 / 32), blk, 0, stream>>>(Wqr,  Wqr_t,  512, 8192);
    tconv<<<dim3(512 / 32, 2048 / 32), blk, 0, stream>>>(Wkr,  Wkr_t,  2048, 512);
    tconv<<<dim3(2048 / 32, 2048 / 32), blk, 0, stream>>>(Wfc, Wfc_t,  2048, 2048);

    auto mkargs = [](const u16* A0, int ldA0, int K0, const u16* B0, int ldB0,
                     const float* bias, void* C, int ldc, int flags) {
        GArgs a{};
        a.A0 = A0; a.B0 = B0; a.A1 = nullptr; a.B1 = nullptr;
        a.ldA0 = ldA0; a.ldB0 = ldB0; a.K0 = K0; a.K1 = 0;
        a.bias = bias; a.C = C; a.ldc = ldc;
        a.innerCnt = 1; a.flags = flags; a.scale = 1.f;
        return a;
    };

    // ---- projection GEMMs ----
    {   // c_q = X @ Wdq + bdq
        GArgs a = mkargs(Xb, 2048, 2048, Wdq_t, 2048, bdq, c_q, 512, 0);
        gemm_mfma<<<dim3(4, 32, 1), blk, 0, stream>>>(a);
    }
    {   // c_kv
        GArgs a = mkargs(Xb, 2048, 2048, Wdkv_t, 2048, bdkv, c_kv, 512, 0);
        gemm_mfma<<<dim3(4, 32, 1), blk, 0, stream>>>(a);
    }
    {   // q_c = c_q @ Wuq + buq
        GArgs a = mkargs(c_q, 512, 512, Wuq_t, 512, buq, q_c, 2048, 0);
        gemm_mfma<<<dim3(16, 32, 1), blk, 0, stream>>>(a);
    }
    {   // k_c
        GArgs a = mkargs(c_kv, 512, 512, Wuk_t, 512, buk, k_c, 2048, 0);
        gemm_mfma<<<dim3(16, 32, 1), blk, 0, stream>>>(a);
    }
    {   // v^T (transposed write): v_t[hd][bs]
        GArgs a = mkargs(c_kv, 512, 512, Wuv_t, 512, buv, v_t, 4096, FLAG_TRANSC);
        gemm_mfma<<<dim3(16, 32, 1), blk, 0, stream>>>(a);
    }
    {   // q_r = rope(c_q @ Wqr + bqr)
        GArgs a = mkargs(c_q, 512, 512, Wqr_t, 512, bqr, q_r, 8192, FLAG_ROPE);
        gemm_mfma<<<dim3(64, 32, 1), blk, 0, stream>>>(a);
    }
    {   // k_r = rope(X @ Wkr + bkr)
        GArgs a = mkargs(Xb, 2048, 2048, Wkr_t, 2048, bkr, k_r, 512, FLAG_ROPE);
        gemm_mfma<<<dim3(4, 32, 1), blk, 0, stream>>>(a);
    }

    // ---- attention, two batch-halves (attn buffer = 64 z-slices) ----
    for (int half = 0; half < 2; ++half) {
        long b0 = half * 4;
        {   // scores: qc.kc^T (K=128) + qr.kr^T (K=512), scaled
            GArgs a{};
            a.A0 = q_c + b0 * 1048576; a.sA0o = 1048576; a.sA0i = 128; a.ldA0 = 2048; a.K0 = 128;
            a.B0 = k_c + b0 * 1048576; a.sB0o = 1048576; a.sB0i = 128; a.ldB0 = 2048;
            a.A1 = q_r + b0 * 4194304; a.sA1o = 4194304; a.sA1i = 512; a.ldA1 = 8192; a.K1 = 512;
            a.B1 = k_r + b0 * 262144;  a.sB1o = 262144;  a.sB1i = 0;   a.ldB1 = 512;
            a.bias = nullptr;
            a.C = attn; a.sCo = 16l * 262144; a.sCi = 262144; a.ldc = 512;
            a.innerCnt = 16; a.flags = FLAG_SCALE;
            a.scale = 1.0f / 33.941125496954285f;   // 1/(sqrt(128)+sqrt(512))
            gemm_mfma<<<dim3(4, 4, 64), blk, 0, stream>>>(a);
        }
        softmax_rows<<<dim3(64 * 512 / 4, 1, 1), blk, 0, stream>>>(attn);
        {   // o = attn @ V  (B = v_t slice, NT)
            GArgs a{};
            a.A0 = attn; a.sA0o = 16l * 262144; a.sA0i = 262144; a.ldA0 = 512; a.K0 = 512;
            a.B0 = v_t + b0 * 512; a.sB0o = 512; a.sB0i = 128l * 4096; a.ldB0 = 4096;
            a.A1 = nullptr; a.B1 = nullptr; a.K1 = 0;
            a.bias = nullptr;
            a.C = o + b0 * 1048576; a.sCo = 1048576; a.sCi = 128; a.ldc = 2048;
            a.innerCnt = 16; a.flags = 0; a.scale = 1.f;
            gemm_mfma<<<dim3(1, 4, 64), blk, 0, stream>>>(a);
        }
    }

    // ---- final projection (fp32 out) ----
    {
        GArgs a = mkargs(o, 2048, 2048, Wfc_t, 2048, bfc, out, 2048, FLAG_F32OUT);
        gemm_mfma<<<dim3(16, 32, 1), blk, 0, stream>>>(a);
    }
}

// Round 4
// 584.729 us; speedup vs baseline: 4.2057x; 1.3208x over previous
//
#include <hip/hip_runtime.h>
#include <hip/hip_bf16.h>
#include <stdint.h>

typedef unsigned short u16;
typedef short bf16x8 __attribute__((ext_vector_type(8)));
typedef float f32x4 __attribute__((ext_vector_type(4)));

__device__ __forceinline__ float us2f(u16 u) {
    union { unsigned int i; float f; } x;
    x.i = ((unsigned int)u) << 16;
    return x.f;
}

__device__ __forceinline__ u16 f2us(float f) {
    union { float f; unsigned int i; } x; x.f = f;
    unsigned int lsb = (x.i >> 16) & 1u;
    x.i += 0x7FFFu + lsb;            // round-to-nearest-even
    return (u16)(x.i >> 16);
}

// async global->LDS, 16B per lane. LDS dest = wave-uniform base + lane*16.
__device__ __forceinline__ void gl_lds16(const u16* g, u16* l) {
    __builtin_amdgcn_global_load_lds(
        (const __attribute__((address_space(1))) void*)(uintptr_t)(const void*)g,
        (__attribute__((address_space(3))) void*)(uintptr_t)(void*)l,
        16, 0, 0);
}

#define FLAG_ROPE   1
#define FLAG_SCALE  2
#define FLAG_TRANSC 4
#define FLAG_F32OUT 8

struct GArgs {
    const u16 *A0, *B0, *A1, *B1;
    long sA0o, sA0i, sB0o, sB0i, sA1o, sA1i, sB1o, sB1i;
    int K0, K1;
    const float* bias;
    void* C; long sCo, sCi;
    int innerCnt;
    float scale;
};

// ---------------------------------------------------------------------------
// NT MFMA GEMM, fully specialized strides: C[m,n] = sum_k A[m,k]*Bt[n,k]
// (+ optional 2nd K-segment when LDA1 != 0).
// 128x128 tile, BK=64, 256 threads = 4 waves 2x2, each wave 64x64 (4x4 MFMA).
// bf16 in (both operands K-major), fp32 accum, bf16/f32 out, fused epilogues.
// Requires M%128==0, N%128==0, K0%64==0, K1%64==0.
// ---------------------------------------------------------------------------
template <int LDA0, int LDB0, int LDC, int FLAGS, int LDA1, int LDB1>
__global__ __launch_bounds__(256)
void gemm_mfma(GArgs g)
{
    __shared__ u16 As[128 * 64];   // 16 KB
    __shared__ u16 Bs[128 * 64];   // 16 KB

    const int t    = threadIdx.x;
    const int lane = t & 63;
    const int w    = t >> 6;
    const int wm   = w >> 1, wn = w & 1;
    const int m0   = blockIdx.y * 128;
    const int n0   = blockIdx.x * 128;

    const int z  = blockIdx.z;
    const int zo = z / g.innerCnt, zi = z - zo * g.innerCnt;

    // staging geometry: 1024 chunks of 16B per operand tile (128 rows x 128B).
    // thread t, issue r covers chunk (r*256 + t): row = r*32 + (t>>3), slot = t&7.
    // slot sp stores global chunk gc = (sp - (row>>1)) & 7  (XOR-free rotation).
    const int srow = t >> 3;
    const int sp   = t & 7;
    u16* dA = As + t * 8;
    u16* dB = Bs + t * 8;

    // fragment read geometry
    const int lr    = lane & 15;
    const int jj    = lane >> 4;
    const int shift = lr >> 1;      // 0..7

    f32x4 acc[4][4];
#pragma unroll
    for (int i = 0; i < 4; ++i)
#pragma unroll
        for (int j = 0; j < 4; ++j)
            acc[i][j] = (f32x4){0.f, 0.f, 0.f, 0.f};

    auto mfma_tile = [&]() {
#pragma unroll
        for (int s = 0; s < 2; ++s) {
            bf16x8 af[4], bfr[4];
#pragma unroll
            for (int mi = 0; mi < 4; ++mi) {
                int row  = wm * 64 + mi * 16 + lr;
                int slot = (s * 4 + jj + shift) & 7;
                af[mi] = *(const bf16x8*)&As[row * 64 + slot * 8];
            }
#pragma unroll
            for (int ni = 0; ni < 4; ++ni) {
                int row  = wn * 64 + ni * 16 + lr;
                int slot = (s * 4 + jj + shift) & 7;
                bfr[ni] = *(const bf16x8*)&Bs[row * 64 + slot * 8];
            }
#pragma unroll
            for (int mi = 0; mi < 4; ++mi)
#pragma unroll
                for (int ni = 0; ni < 4; ++ni)
                    acc[mi][ni] = __builtin_amdgcn_mfma_f32_16x16x32_bf16(
                        af[mi], bfr[ni], acc[mi][ni], 0, 0, 0);
        }
    };

    {   // segment 0
        const u16* A = g.A0 + zo * g.sA0o + zi * g.sA0i;
        const u16* B = g.B0 + zo * g.sB0o + zi * g.sB0i;
        const u16* gA[4];
        const u16* gB[4];
#pragma unroll
        for (int r = 0; r < 4; ++r) {
            int row = r * 32 + srow;
            int gc  = (sp - (row >> 1)) & 7;
            gA[r] = A + (long)(m0 + row) * LDA0 + gc * 8;
            gB[r] = B + (long)(n0 + row) * LDB0 + gc * 8;
        }
        for (int kt = 0; kt < g.K0; kt += 64) {
#pragma unroll
            for (int r = 0; r < 4; ++r) {
                gl_lds16(gA[r], dA + r * 2048);
                gl_lds16(gB[r], dB + r * 2048);
                gA[r] += 64; gB[r] += 64;
            }
            __syncthreads();
            mfma_tile();
            __syncthreads();
        }
    }

    if (LDA1 != 0) {   // segment 1 (scores rope part)
        const u16* A = g.A1 + zo * g.sA1o + zi * g.sA1i;
        const u16* B = g.B1 + zo * g.sB1o + zi * g.sB1i;
        const u16* gA[4];
        const u16* gB[4];
#pragma unroll
        for (int r = 0; r < 4; ++r) {
            int row = r * 32 + srow;
            int gc  = (sp - (row >> 1)) & 7;
            gA[r] = A + (long)(m0 + row) * (LDA1 ? LDA1 : 1) + gc * 8;
            gB[r] = B + (long)(n0 + row) * (LDB1 ? LDB1 : 1) + gc * 8;
        }
        for (int kt = 0; kt < g.K1; kt += 64) {
#pragma unroll
            for (int r = 0; r < 4; ++r) {
                gl_lds16(gA[r], dA + r * 2048);
                gl_lds16(gB[r], dB + r * 2048);
                gA[r] += 64; gB[r] += 64;
            }
            __syncthreads();
            mfma_tile();
            __syncthreads();
        }
    }

    // epilogue. C/D layout: col = lane&15, row = (lane>>4)*4 + reg.
    const int esz = (FLAGS & FLAG_F32OUT) ? 4 : 2;
    char* Cb = (char*)g.C + (zo * g.sCo + zi * g.sCi) * esz;
    const int eCol0 = n0 + wn * 64 + lr;
    const int eRow0 = m0 + wm * 64 + jj * 4;
    const bool oddc = lane & 1;

    float biasv[4];
    if (g.bias) {
#pragma unroll
        for (int ni = 0; ni < 4; ++ni) biasv[ni] = g.bias[eCol0 + ni * 16];
    }

#pragma unroll
    for (int mi = 0; mi < 4; ++mi) {
#pragma unroll
        for (int ni = 0; ni < 4; ++ni) {
            f32x4 v = acc[mi][ni];
            if (g.bias) {
                float bv = biasv[ni];
                v[0] += bv; v[1] += bv; v[2] += bv; v[3] += bv;
            }
            if (FLAGS & FLAG_SCALE) {
                v[0] *= g.scale; v[1] *= g.scale; v[2] *= g.scale; v[3] *= g.scale;
            }
            if (FLAGS & FLAG_ROPE) {
                int col = eCol0 + ni * 16;
                int rp  = (col & 511) & ~1;
                float freq = __expf(-9.2103403719761836f * (float)rp * (1.0f / 512.0f));
#pragma unroll
                for (int i = 0; i < 4; ++i) {
                    int row = eRow0 + mi * 16 + i;
                    float th = (float)(row & 511) * freq;
                    float sn, cs;
                    __sincosf(th, &sn, &cs);
                    float other = __shfl_xor(v[i], 1, 64);
                    v[i] = oddc ? (v[i] * cs + other * sn)
                                : (v[i] * cs - other * sn);
                }
            }
            int rowb = eRow0 + mi * 16;
            int col  = eCol0 + ni * 16;
            if (FLAGS & FLAG_TRANSC) {
                u16* cp = (u16*)Cb + (long)col * LDC + rowb;
                ushort4 o4;
                o4.x = f2us(v[0]); o4.y = f2us(v[1]);
                o4.z = f2us(v[2]); o4.w = f2us(v[3]);
                *(ushort4*)cp = o4;
            } else if (FLAGS & FLAG_F32OUT) {
                float* cp = (float*)Cb;
#pragma unroll
                for (int i = 0; i < 4; ++i)
                    cp[(long)(rowb + i) * LDC + col] = v[i];
            } else {
                u16* cp = (u16*)Cb;
#pragma unroll
                for (int i = 0; i < 4; ++i)
                    cp[(long)(rowb + i) * LDC + col] = f2us(v[i]);
            }
        }
    }
}

// ---------------------------------------------------------------------------
// fp32 -> bf16 elementwise (vectorized x4)
// ---------------------------------------------------------------------------
__global__ __launch_bounds__(256)
void conv_f32_bf16(const float* __restrict__ in, u16* __restrict__ out)
{
    int i = blockIdx.x * 256 + threadIdx.x;
    float4 v = ((const float4*)in)[i];
    ushort4 o;
    o.x = f2us(v.x); o.y = f2us(v.y); o.z = f2us(v.z); o.w = f2us(v.w);
    ((ushort4*)out)[i] = o;
}

// ---------------------------------------------------------------------------
// fp32 [K][N] -> bf16 [N][K] transpose-convert, 32x32 LDS tile
// ---------------------------------------------------------------------------
__global__ __launch_bounds__(256)
void tconv(const float* __restrict__ in, u16* __restrict__ out, int K, int N)
{
    __shared__ float tile[32][33];
    int n0 = blockIdx.x * 32, k0 = blockIdx.y * 32;
    int c = threadIdx.x & 31, r0 = threadIdx.x >> 5;
#pragma unroll
    for (int j = 0; j < 4; ++j) {
        int r = r0 + j * 8;
        tile[r][c] = in[(long)(k0 + r) * N + n0 + c];
    }
    __syncthreads();
#pragma unroll
    for (int j = 0; j < 4; ++j) {
        int r = r0 + j * 8;
        out[(long)(n0 + r) * K + k0 + c] = f2us(tile[c][r]);
    }
}

// ---------------------------------------------------------------------------
// Row softmax in-place over rows of 512 (one wave per row, 4 rows/block)
// ---------------------------------------------------------------------------
__global__ __launch_bounds__(256)
void softmax_rows(u16* __restrict__ attn)
{
    int row  = blockIdx.x * 4 + (threadIdx.x >> 6);
    int lane = threadIdx.x & 63;
    u16* p = attn + (long)row * 512;

    float v[8];
#pragma unroll
    for (int i = 0; i < 8; ++i) v[i] = us2f(p[lane + (i << 6)]);

    float mx = v[0];
#pragma unroll
    for (int i = 1; i < 8; ++i) mx = fmaxf(mx, v[i]);
#pragma unroll
    for (int off = 32; off >= 1; off >>= 1)
        mx = fmaxf(mx, __shfl_xor(mx, off, 64));

    float e[8], s = 0.f;
#pragma unroll
    for (int i = 0; i < 8; ++i) { e[i] = __expf(v[i] - mx); s += e[i]; }
#pragma unroll
    for (int off = 32; off >= 1; off >>= 1)
        s += __shfl_xor(s, off, 64);

    float inv = 1.0f / s;
#pragma unroll
    for (int i = 0; i < 8; ++i) p[lane + (i << 6)] = f2us(e[i] * inv);
}

// ---------------------------------------------------------------------------
extern "C" void kernel_launch(void* const* d_in, const int* in_sizes, int n_in,
                              void* d_out, int out_size, void* d_ws, size_t ws_size,
                              hipStream_t stream)
{
    (void)in_sizes; (void)n_in; (void)out_size; (void)ws_size;

    const float* X    = (const float*)d_in[0];
    const float* Wdq  = (const float*)d_in[1];  const float* bdq  = (const float*)d_in[2];
    const float* Wdkv = (const float*)d_in[3];  const float* bdkv = (const float*)d_in[4];
    const float* Wuq  = (const float*)d_in[5];  const float* buq  = (const float*)d_in[6];
    const float* Wuk  = (const float*)d_in[7];  const float* buk  = (const float*)d_in[8];
    const float* Wuv  = (const float*)d_in[9];  const float* buv  = (const float*)d_in[10];
    const float* Wqr  = (const float*)d_in[11]; const float* bqr  = (const float*)d_in[12];
    const float* Wkr  = (const float*)d_in[13]; const float* bkr  = (const float*)d_in[14];
    const float* Wfc  = (const float*)d_in[15]; const float* bfc  = (const float*)d_in[16];
    float* out = (float*)d_out;

    // workspace (u16 elems). region0 (Xb + Wt except Wfc) is reused as attn.
    u16* ws = (u16*)d_ws;
    u16* Xb     = ws;                 // 4096x2048            (8M)
    u16* Wdq_t  = Xb     + 8388608;   // [512][2048]          (1M)
    u16* Wdkv_t = Wdq_t  + 1048576;   // [512][2048]          (1M)
    u16* Wuq_t  = Wdkv_t + 1048576;   // [2048][512]          (1M)
    u16* Wuk_t  = Wuq_t  + 1048576;   // [2048][512]          (1M)
    u16* Wuv_t  = Wuk_t  + 1048576;   // [2048][512]          (1M)
    u16* Wqr_t  = Wuv_t  + 1048576;   // [8192][512]          (4M)
    u16* Wkr_t  = Wqr_t  + 4194304;   // [512][2048]          (1M)
    u16* attn   = Xb;                 // 64x512x512 = 16M  (aliases region0: 18M)
    u16* Wfc_t  = Wkr_t  + 1048576;   // [2048][2048]         (4M)
    u16* c_q    = Wfc_t  + 4194304;   // [4096][512]          (2M)
    u16* c_kv   = c_q    + 2097152;   // [4096][512]          (2M)
    u16* q_c    = c_kv   + 2097152;   // [4096][2048]         (8M)
    u16* k_c    = q_c    + 8388608;   // [4096][2048]         (8M)
    u16* v_t    = k_c    + 8388608;   // [2048][4096] (V^T)   (8M)
    u16* q_r    = v_t    + 8388608;   // [4096][8192]         (32M)
    u16* k_r    = q_r    + 33554432;  // [4096][512]          (2M)
    u16* o      = k_r    + 2097152;   // [4096][2048]         (8M)

    dim3 blk(256, 1, 1);

    // ---- converts ----
    conv_f32_bf16<<<8192, blk, 0, stream>>>(X, Xb);
    tconv<<<dim3(512 / 32, 2048 / 32), blk, 0, stream>>>(Wdq,  Wdq_t,  2048, 512);
    tconv<<<dim3(512 / 32, 2048 / 32), blk, 0, stream>>>(Wdkv, Wdkv_t, 2048, 512);
    tconv<<<dim3(2048 / 32, 512 / 32), blk, 0, stream>>>(Wuq,  Wuq_t,  512, 2048);
    tconv<<<dim3(2048 / 32, 512 / 32), blk, 0, stream>>>(Wuk,  Wuk_t,  512, 2048);
    tconv<<<dim3(2048 / 32, 512 / 32), blk, 0, stream>>>(Wuv,  Wuv_t,  512, 2048);
    tconv<<<dim3(8192 / 32, 512 / 32), blk, 0, stream>>>(Wqr,  Wqr_t,  512, 8192);
    tconv<<<dim3(512 / 32, 2048 / 32), blk, 0, stream>>>(Wkr,  Wkr_t,  2048, 512);
    tconv<<<dim3(2048 / 32, 2048 / 32), blk, 0, stream>>>(Wfc, Wfc_t,  2048, 2048);

    auto base = [](const u16* A0, const u16* B0, int K0, const float* bias,
                   void* C) {
        GArgs a{};
        a.A0 = A0; a.B0 = B0; a.K0 = K0; a.bias = bias; a.C = C;
        a.innerCnt = 1; a.scale = 1.f;
        return a;
    };

    {   // c_q = X @ Wdq + bdq
        GArgs a = base(Xb, Wdq_t, 2048, bdq, c_q);
        gemm_mfma<2048, 2048, 512, 0, 0, 0><<<dim3(4, 32, 1), blk, 0, stream>>>(a);
    }
    {   // c_kv
        GArgs a = base(Xb, Wdkv_t, 2048, bdkv, c_kv);
        gemm_mfma<2048, 2048, 512, 0, 0, 0><<<dim3(4, 32, 1), blk, 0, stream>>>(a);
    }
    {   // q_c = c_q @ Wuq + buq
        GArgs a = base(c_q, Wuq_t, 512, buq, q_c);
        gemm_mfma<512, 512, 2048, 0, 0, 0><<<dim3(16, 32, 1), blk, 0, stream>>>(a);
    }
    {   // k_c
        GArgs a = base(c_kv, Wuk_t, 512, buk, k_c);
        gemm_mfma<512, 512, 2048, 0, 0, 0><<<dim3(16, 32, 1), blk, 0, stream>>>(a);
    }
    {   // v^T (transposed write): v_t[hd][bs]
        GArgs a = base(c_kv, Wuv_t, 512, buv, v_t);
        gemm_mfma<512, 512, 4096, FLAG_TRANSC, 0, 0><<<dim3(16, 32, 1), blk, 0, stream>>>(a);
    }
    {   // q_r = rope(c_q @ Wqr + bqr)
        GArgs a = base(c_q, Wqr_t, 512, bqr, q_r);
        gemm_mfma<512, 512, 8192, FLAG_ROPE, 0, 0><<<dim3(64, 32, 1), blk, 0, stream>>>(a);
    }
    {   // k_r = rope(X @ Wkr + bkr)
        GArgs a = base(Xb, Wkr_t, 2048, bkr, k_r);
        gemm_mfma<2048, 2048, 512, FLAG_ROPE, 0, 0><<<dim3(4, 32, 1), blk, 0, stream>>>(a);
    }

    // ---- attention, two batch-halves (attn buffer = 64 z-slices) ----
    for (int half = 0; half < 2; ++half) {
        long b0 = half * 4;
        {   // scores: qc.kc^T (K=128) + qr.kr^T (K=512), scaled
            GArgs a{};
            a.A0 = q_c + b0 * 1048576; a.sA0o = 1048576; a.sA0i = 128; a.K0 = 128;
            a.B0 = k_c + b0 * 1048576; a.sB0o = 1048576; a.sB0i = 128;
            a.A1 = q_r + b0 * 4194304; a.sA1o = 4194304; a.sA1i = 512; a.K1 = 512;
            a.B1 = k_r + b0 * 262144;  a.sB1o = 262144;  a.sB1i = 0;
            a.C = attn; a.sCo = 16l * 262144; a.sCi = 262144;
            a.innerCnt = 16;
            a.scale = 1.0f / 33.941125496954285f;   // 1/(sqrt(128)+sqrt(512))
            gemm_mfma<2048, 2048, 512, FLAG_SCALE, 8192, 512>
                <<<dim3(4, 4, 64), blk, 0, stream>>>(a);
        }
        softmax_rows<<<dim3(64 * 512 / 4, 1, 1), blk, 0, stream>>>(attn);
        {   // o = attn @ V  (B = v_t slice, NT)
            GArgs a{};
            a.A0 = attn; a.sA0o = 16l * 262144; a.sA0i = 262144; a.K0 = 512;
            a.B0 = v_t + b0 * 512; a.sB0o = 512; a.sB0i = 128l * 4096;
            a.C = o + b0 * 1048576; a.sCo = 1048576; a.sCi = 128;
            a.innerCnt = 16; a.scale = 1.f;
            gemm_mfma<512, 4096, 2048, 0, 0, 0><<<dim3(1, 4, 64), blk, 0, stream>>>(a);
        }
    }

    // ---- final projection (fp32 out) ----
    {
        GArgs a = base(o, Wfc_t, 2048, bfc, out);
        gemm_mfma<2048, 2048, 2048, FLAG_F32OUT, 0, 0><<<dim3(16, 32, 1), blk, 0, stream>>>(a);
    }
}

// Round 5
// 481.349 us; speedup vs baseline: 5.1090x; 1.2148x over previous
//
#include <hip/hip_runtime.h>
#include <hip/hip_bf16.h>
#include <stdint.h>

typedef unsigned short u16;
typedef short bf16x8 __attribute__((ext_vector_type(8)));
typedef float f32x4 __attribute__((ext_vector_type(4)));

__device__ __forceinline__ float us2f(u16 u) {
    union { unsigned int i; float f; } x;
    x.i = ((unsigned int)u) << 16;
    return x.f;
}

__device__ __forceinline__ u16 f2us(float f) {
    union { float f; unsigned int i; } x; x.f = f;
    unsigned int lsb = (x.i >> 16) & 1u;
    x.i += 0x7FFFu + lsb;            // round-to-nearest-even
    return (u16)(x.i >> 16);
}

// async global->LDS, 16B per lane. LDS dest = wave-uniform base + lane*16.
__device__ __forceinline__ void gl_lds16(const u16* g, u16* l) {
    __builtin_amdgcn_global_load_lds(
        (const __attribute__((address_space(1))) void*)(uintptr_t)(const void*)g,
        (__attribute__((address_space(3))) void*)(uintptr_t)(void*)l,
        16, 0, 0);
}

#define FLAG_ROPE2  1   // region2 cols get interleaved RoPE (head_dim 512)
#define FLAG_SCALE  2   // multiply by g.scale (region1)
#define FLAG_TRANS2 4   // region2 written transposed (ldc2 = rows stride)
#define FLAG_F32OUT 8   // region1 written fp32

struct GArgs {
    const u16 *A0, *B0, *B0r2, *A1, *B1;
    long sA0o, sA0i, sB0o, sB0i, sA1o, sA1i, sB1o, sB1i;
    int K0, K1;
    const float* bias;          // indexed by global col (concatenated)
    void* C; void* C2; long sCo, sCi;
    int colSplit;               // cols >= colSplit -> region2 (multiple of 128)
    int innerCnt;
    float scale;
};

// ---------------------------------------------------------------------------
// NT MFMA GEMM: C[m,n] = sum_k A[m,k]*Bt[n,k] (+ optional 2nd K-segment).
// 128x128 tile, BK=64, 256 threads = 4 waves 2x2, each wave 64x64 (4x4 MFMA).
// bf16 in (K-major both sides), fp32 accum. Column-split epilogue: cols >=
// colSplit go to C2 (optionally RoPE'd or transposed). B region2 rows come
// from B0r2. Requires M%128==0, N%128==0, K%64==0.
// LDS chunk rotation: slot s of row r holds chunk (s - r) & 7  -> 8
// consecutive reading lanes cover all 8 bank groups (conflict-free).
// ---------------------------------------------------------------------------
template <int LDA0, int LDB0, int LDC, int LDC2, int FLAGS, int LDA1, int LDB1>
__global__ __launch_bounds__(256)
void gemm_mfma(GArgs g)
{
    __shared__ u16 As[128 * 64];   // 16 KB
    __shared__ u16 Bs[128 * 64];   // 16 KB

    const int t    = threadIdx.x;
    const int lane = t & 63;
    const int w    = t >> 6;
    const int wm   = w >> 1, wn = w & 1;
    const int m0   = blockIdx.y * 128;
    const int n0   = blockIdx.x * 128;
    const bool r2  = (n0 >= g.colSplit);

    const int z  = blockIdx.z;
    const int zo = z / g.innerCnt, zi = z - zo * g.innerCnt;

    const int srow = t >> 3;    // 0..31 base row for staging
    const int sp   = t & 7;     // LDS slot within row
    u16* dA = As + t * 8;
    u16* dB = Bs + t * 8;

    const int lr = lane & 15;
    const int jj = lane >> 4;

    f32x4 acc[4][4];
#pragma unroll
    for (int i = 0; i < 4; ++i)
#pragma unroll
        for (int j = 0; j < 4; ++j)
            acc[i][j] = (f32x4){0.f, 0.f, 0.f, 0.f};

    auto mfma_tile = [&]() {
#pragma unroll
        for (int s = 0; s < 2; ++s) {
            bf16x8 af[4], bfr[4];
#pragma unroll
            for (int mi = 0; mi < 4; ++mi) {
                int row  = wm * 64 + mi * 16 + lr;
                int slot = (s * 4 + jj + row) & 7;
                af[mi] = *(const bf16x8*)&As[row * 64 + slot * 8];
            }
#pragma unroll
            for (int ni = 0; ni < 4; ++ni) {
                int row  = wn * 64 + ni * 16 + lr;
                int slot = (s * 4 + jj + row) & 7;
                bfr[ni] = *(const bf16x8*)&Bs[row * 64 + slot * 8];
            }
#pragma unroll
            for (int mi = 0; mi < 4; ++mi)
#pragma unroll
                for (int ni = 0; ni < 4; ++ni)
                    acc[mi][ni] = __builtin_amdgcn_mfma_f32_16x16x32_bf16(
                        af[mi], bfr[ni], acc[mi][ni], 0, 0, 0);
        }
    };

    {   // segment 0
        const u16* A = g.A0 + zo * g.sA0o + zi * g.sA0i;
        const u16* B = (r2 ? g.B0r2 - (long)g.colSplit * LDB0 : g.B0)
                       + zo * g.sB0o + zi * g.sB0i;
        const u16* gA[4];
        const u16* gB[4];
#pragma unroll
        for (int r = 0; r < 4; ++r) {
            int row = r * 32 + srow;
            int gc  = (sp - row) & 7;
            gA[r] = A + (long)(m0 + row) * LDA0 + gc * 8;
            gB[r] = B + (long)(n0 + row) * LDB0 + gc * 8;
        }
        for (int kt = 0; kt < g.K0; kt += 64) {
#pragma unroll
            for (int r = 0; r < 4; ++r) {
                gl_lds16(gA[r], dA + r * 2048);
                gl_lds16(gB[r], dB + r * 2048);
                gA[r] += 64; gB[r] += 64;
            }
            __syncthreads();
            mfma_tile();
            __syncthreads();
        }
    }

    if (LDA1 != 0) {   // segment 1 (scores rope part)
        const u16* A = g.A1 + zo * g.sA1o + zi * g.sA1i;
        const u16* B = g.B1 + zo * g.sB1o + zi * g.sB1i;
        const u16* gA[4];
        const u16* gB[4];
#pragma unroll
        for (int r = 0; r < 4; ++r) {
            int row = r * 32 + srow;
            int gc  = (sp - row) & 7;
            gA[r] = A + (long)(m0 + row) * (LDA1 ? LDA1 : 1) + gc * 8;
            gB[r] = B + (long)(n0 + row) * (LDB1 ? LDB1 : 1) + gc * 8;
        }
        for (int kt = 0; kt < g.K1; kt += 64) {
#pragma unroll
            for (int r = 0; r < 4; ++r) {
                gl_lds16(gA[r], dA + r * 2048);
                gl_lds16(gB[r], dB + r * 2048);
                gA[r] += 64; gB[r] += 64;
            }
            __syncthreads();
            mfma_tile();
            __syncthreads();
        }
    }

    // epilogue. C/D layout: col = lane&15, row = (lane>>4)*4 + reg.
    const int eCol0 = n0 + wn * 64 + lr;
    const int eRow0 = m0 + wm * 64 + jj * 4;
    const bool oddc = lane & 1;

    float biasv[4];
    if (g.bias) {
#pragma unroll
        for (int ni = 0; ni < 4; ++ni) biasv[ni] = g.bias[eCol0 + ni * 16];
    }

#pragma unroll
    for (int mi = 0; mi < 4; ++mi) {
#pragma unroll
        for (int ni = 0; ni < 4; ++ni) {
            f32x4 v = acc[mi][ni];
            if (g.bias) {
                float bv = biasv[ni];
                v[0] += bv; v[1] += bv; v[2] += bv; v[3] += bv;
            }
            if (FLAGS & FLAG_SCALE) {
                v[0] *= g.scale; v[1] *= g.scale; v[2] *= g.scale; v[3] *= g.scale;
            }
            const int colg = eCol0 + ni * 16;
            const int rowb = eRow0 + mi * 16;
            if (!r2) {
                if (FLAGS & FLAG_F32OUT) {
                    float* cp = (float*)g.C + zo * g.sCo + zi * g.sCi;
#pragma unroll
                    for (int i = 0; i < 4; ++i)
                        cp[(long)(rowb + i) * LDC + colg] = v[i];
                } else {
                    u16* cp = (u16*)g.C + zo * g.sCo + zi * g.sCi;
#pragma unroll
                    for (int i = 0; i < 4; ++i)
                        cp[(long)(rowb + i) * LDC + colg] = f2us(v[i]);
                }
            } else {
                const int col2 = colg - g.colSplit;
                if (FLAGS & FLAG_ROPE2) {
                    int rp = col2 & 511 & ~1;
                    float freq = __expf(-9.2103403719761836f * (float)rp * (1.0f / 512.0f));
#pragma unroll
                    for (int i = 0; i < 4; ++i) {
                        float th = (float)((rowb + i) & 511) * freq;
                        float sn, cs;
                        __sincosf(th, &sn, &cs);
                        float other = __shfl_xor(v[i], 1, 64);
                        v[i] = oddc ? (v[i] * cs + other * sn)
                                    : (v[i] * cs - other * sn);
                    }
                }
                if (FLAGS & FLAG_TRANS2) {
                    u16* cp = (u16*)g.C2 + (long)col2 * LDC2 + rowb;
                    ushort4 o4;
                    o4.x = f2us(v[0]); o4.y = f2us(v[1]);
                    o4.z = f2us(v[2]); o4.w = f2us(v[3]);
                    *(ushort4*)cp = o4;
                } else {
                    u16* cp = (u16*)g.C2;
#pragma unroll
                    for (int i = 0; i < 4; ++i)
                        cp[(long)(rowb + i) * LDC2 + col2] = f2us(v[i]);
                }
            }
        }
    }
}

// ---------------------------------------------------------------------------
// Fused softmax + PV. Per block: one (b,h) slice, 32 q-rows, all 512 keys.
// Stage raw scaled scores 32x512 bf16 in LDS (rotated slots), in-LDS
// softmax (exp, keep unnormalized, row sums in l_arr), then O = P·V via
// MFMA off LDS; epilogue divides by l. attn holds RAW scaled scores.
// ---------------------------------------------------------------------------
__global__ __launch_bounds__(256)
void pv_soft(const u16* __restrict__ attn, const u16* __restrict__ v_t,
             u16* __restrict__ o, int b0)
{
    __shared__ u16 Ae[32 * 512];   // 32 KB, slot s of row r = chunk (s-r)&63
    __shared__ u16 Bv[128 * 64];   // 16 KB, slot s of row r = chunk (s-r)&7
    __shared__ float l_arr[32];

    const int t    = threadIdx.x;
    const int lane = t & 63;
    const int w    = t >> 6;
    const int z    = blockIdx.y;          // 0..63 chunk-local (b,h)
    const int bb   = b0 + (z >> 4);
    const int h    = z & 15;
    const int m0   = blockIdx.x * 32;

    // ---- phase 1: stage scores rows (wave w -> rows w*8 .. w*8+7) ----
    const u16* Abase = attn + (long)z * 262144 + (long)m0 * 512;
#pragma unroll
    for (int i = 0; i < 8; ++i) {
        int row = w * 8 + i;
        int gc  = (lane - row) & 63;
        gl_lds16(Abase + (long)row * 512 + gc * 8, Ae + row * 512 + lane * 8);
    }
    __syncthreads();

    // ---- phase 2: in-LDS softmax (8 threads per row) ----
    {
        int r = t >> 3, p = t & 7;
        u16* rp_ = Ae + r * 512;
        float mx = -1e30f;
#pragma unroll
        for (int j = 0; j < 8; ++j) {
            int slot = (p + 8 * j + r) & 63;
            bf16x8 vv = *(const bf16x8*)&rp_[slot * 8];
#pragma unroll
            for (int e = 0; e < 8; ++e) mx = fmaxf(mx, us2f(((u16*)&vv)[e]));
        }
        mx = fmaxf(mx, __shfl_xor(mx, 1, 64));
        mx = fmaxf(mx, __shfl_xor(mx, 2, 64));
        mx = fmaxf(mx, __shfl_xor(mx, 4, 64));
        float s = 0.f;
#pragma unroll
        for (int j = 0; j < 8; ++j) {
            int slot = (p + 8 * j + r) & 63;
            bf16x8 vv = *(const bf16x8*)&rp_[slot * 8];
            bf16x8 ov;
#pragma unroll
            for (int e = 0; e < 8; ++e) {
                float ee = __expf(us2f(((u16*)&vv)[e]) - mx);
                s += ee;
                ((u16*)&ov)[e] = f2us(ee);
            }
            *(bf16x8*)&rp_[slot * 8] = ov;
        }
        s += __shfl_xor(s, 1, 64);
        s += __shfl_xor(s, 2, 64);
        s += __shfl_xor(s, 4, 64);
        if (p == 0) l_arr[r] = s;
    }
    __syncthreads();

    // ---- phase 3: O = P·V (NT, B = v_t rows), 8 iters of BK=64 ----
    const int lr = lane & 15;
    const int jj = lane >> 4;
    f32x4 acc[2][2];
#pragma unroll
    for (int i = 0; i < 2; ++i)
#pragma unroll
        for (int j = 0; j < 2; ++j) acc[i][j] = (f32x4){0.f, 0.f, 0.f, 0.f};

    const u16* gB[4];
    u16* dB = Bv + t * 8;
#pragma unroll
    for (int r = 0; r < 4; ++r) {
        int row = r * 32 + (t >> 3);
        int gc  = ((t & 7) - row) & 7;
        gB[r] = v_t + (long)(h * 128 + row) * 4096 + (long)bb * 512 + gc * 8;
    }
    for (int kt = 0; kt < 8; ++kt) {
#pragma unroll
        for (int r = 0; r < 4; ++r) {
            gl_lds16(gB[r], dB + r * 2048);
            gB[r] += 64;
        }
        __syncthreads();
#pragma unroll
        for (int s = 0; s < 2; ++s) {
            int kc = kt * 8 + s * 4 + jj;
            bf16x8 af[2], bfr[2];
#pragma unroll
            for (int mi = 0; mi < 2; ++mi) {
                int rowa = mi * 16 + lr;
                int slot = (kc + rowa) & 63;
                af[mi] = *(const bf16x8*)&Ae[rowa * 512 + slot * 8];
            }
#pragma unroll
            for (int ni = 0; ni < 2; ++ni) {
                int rowb = w * 32 + ni * 16 + lr;
                int slot = (s * 4 + jj + rowb) & 7;
                bfr[ni] = *(const bf16x8*)&Bv[rowb * 64 + slot * 8];
            }
#pragma unroll
            for (int mi = 0; mi < 2; ++mi)
#pragma unroll
                for (int ni = 0; ni < 2; ++ni)
                    acc[mi][ni] = __builtin_amdgcn_mfma_f32_16x16x32_bf16(
                        af[mi], bfr[ni], acc[mi][ni], 0, 0, 0);
        }
        __syncthreads();
    }

    // ---- epilogue: divide by l, write o[bs][h*128 + col] ----
#pragma unroll
    for (int mi = 0; mi < 2; ++mi) {
#pragma unroll
        for (int i = 0; i < 4; ++i) {
            int row_l = mi * 16 + jj * 4 + i;
            float linv = 1.0f / l_arr[row_l];
            long grow = (long)(bb * 512 + m0 + row_l) * 2048 + h * 128;
#pragma unroll
            for (int ni = 0; ni < 2; ++ni) {
                int colc = w * 32 + ni * 16 + lr;
                o[grow + colc] = f2us(acc[mi][ni][i] * linv);
            }
        }
    }
}

// ---------------------------------------------------------------------------
// fp32 -> bf16 elementwise (vectorized x4)
// ---------------------------------------------------------------------------
__global__ __launch_bounds__(256)
void conv_f32_bf16(const float* __restrict__ in, u16* __restrict__ out)
{
    int i = blockIdx.x * 256 + threadIdx.x;
    float4 v = ((const float4*)in)[i];
    ushort4 o;
    o.x = f2us(v.x); o.y = f2us(v.y); o.z = f2us(v.z); o.w = f2us(v.w);
    ((ushort4*)out)[i] = o;
}

// ---------------------------------------------------------------------------
// batched fp32 [K][N] -> bf16 [N][K] transpose-convert, 32x32 LDS tile
// ---------------------------------------------------------------------------
struct TC3 { const float* in0; const float* in1; const float* in2;
             u16* out; long outStride; int K; int N; };

__global__ __launch_bounds__(256)
void tconv3(TC3 a)
{
    __shared__ float tile[32][33];
    const float* in = blockIdx.z == 0 ? a.in0 : (blockIdx.z == 1 ? a.in1 : a.in2);
    u16* out = a.out + blockIdx.z * a.outStride;
    int n0 = blockIdx.x * 32, k0 = blockIdx.y * 32;
    int c = threadIdx.x & 31, r0 = threadIdx.x >> 5;
#pragma unroll
    for (int j = 0; j < 4; ++j) {
        int r = r0 + j * 8;
        tile[r][c] = in[(long)(k0 + r) * a.N + n0 + c];
    }
    __syncthreads();
#pragma unroll
    for (int j = 0; j < 4; ++j) {
        int r = r0 + j * 8;
        out[(long)(n0 + r) * a.K + k0 + c] = f2us(tile[c][r]);
    }
}

// ---------------------------------------------------------------------------
extern "C" void kernel_launch(void* const* d_in, const int* in_sizes, int n_in,
                              void* d_out, int out_size, void* d_ws, size_t ws_size,
                              hipStream_t stream)
{
    (void)in_sizes; (void)n_in; (void)out_size; (void)ws_size;

    const float* X    = (const float*)d_in[0];
    const float* Wdq  = (const float*)d_in[1];  const float* bdq  = (const float*)d_in[2];
    const float* Wdkv = (const float*)d_in[3];  const float* bdkv = (const float*)d_in[4];
    const float* Wuq  = (const float*)d_in[5];  const float* buq  = (const float*)d_in[6];
    const float* Wuk  = (const float*)d_in[7];  const float* buk  = (const float*)d_in[8];
    const float* Wuv  = (const float*)d_in[9];  const float* buv  = (const float*)d_in[10];
    const float* Wqr  = (const float*)d_in[11]; const float* bqr  = (const float*)d_in[12];
    const float* Wkr  = (const float*)d_in[13]; const float* bkr  = (const float*)d_in[14];
    const float* Wfc  = (const float*)d_in[15]; const float* bfc  = (const float*)d_in[16];
    float* out = (float*)d_out;

    // workspace (u16 elems), ~184 MB + small fp32 bias tail
    u16* ws = (u16*)d_ws;
    u16* Xb     = ws;                 // [4096][2048]               8M
    u16* Wc1    = Xb   + 8388608;     // [Wdq_t|Wdkv_t|Wkr_t] = [1536][2048]  3M
    u16* Wc2    = Wc1  + 3145728;     // [Wuq_t|Wuk_t|Wuv_t]  = [6144][512]   3M
    u16* Wqr_t  = Wc2  + 3145728;     // [8192][512]                4M
    u16* attn   = Xb;                 // 64x512x512 = 16M (aliases Xb..Wqr_t = 18M)
    u16* Wfc_t  = Wqr_t + 4194304;    // [2048][2048]               4M
    u16* ckk    = Wfc_t + 4194304;    // [4096][1536] = c_q|c_kv|k_r  6M
    u16* q_c    = ckk  + 6291456;     // [4096][2048]               8M
    u16* k_c    = q_c  + 8388608;     // [4096][2048]               8M
    u16* v_t    = k_c  + 8388608;     // [2048][4096] (V^T)         8M
    u16* q_r    = v_t  + 8388608;     // [4096][8192]               32M
    u16* o      = q_r  + 33554432;    // [4096][2048]               8M
    float* biasD = (float*)(o + 8388608);   // 1536
    float* biasQ = biasD + 1536;            // 10240
    float* biasK = biasQ + 10240;           // 4096

    dim3 blk(256, 1, 1);

    // ---- converts (5 dispatches) + bias concats (async d2d copies) ----
    conv_f32_bf16<<<8192, blk, 0, stream>>>(X, Xb);
    {   TC3 a{Wdq, Wdkv, Wkr, Wc1, 1048576, 2048, 512};
        tconv3<<<dim3(16, 64, 3), blk, 0, stream>>>(a); }
    {   TC3 a{Wuq, Wuk, Wuv, Wc2, 1048576, 512, 2048};
        tconv3<<<dim3(64, 16, 3), blk, 0, stream>>>(a); }
    {   TC3 a{Wqr, nullptr, nullptr, Wqr_t, 0, 512, 8192};
        tconv3<<<dim3(256, 16, 1), blk, 0, stream>>>(a); }
    {   TC3 a{Wfc, nullptr, nullptr, Wfc_t, 0, 2048, 2048};
        tconv3<<<dim3(64, 64, 1), blk, 0, stream>>>(a); }
    hipMemcpyAsync(biasD,        bdq,  512 * 4,  hipMemcpyDeviceToDevice, stream);
    hipMemcpyAsync(biasD + 512,  bdkv, 512 * 4,  hipMemcpyDeviceToDevice, stream);
    hipMemcpyAsync(biasD + 1024, bkr,  512 * 4,  hipMemcpyDeviceToDevice, stream);
    hipMemcpyAsync(biasQ,        buq,  2048 * 4, hipMemcpyDeviceToDevice, stream);
    hipMemcpyAsync(biasQ + 2048, bqr,  8192 * 4, hipMemcpyDeviceToDevice, stream);
    hipMemcpyAsync(biasK,        buk,  2048 * 4, hipMemcpyDeviceToDevice, stream);
    hipMemcpyAsync(biasK + 2048, buv,  2048 * 4, hipMemcpyDeviceToDevice, stream);

    const int NOSPLIT = 1 << 30;

    {   // down-proj: ckk[4096][1536] = X @ [Wdq|Wdkv|Wkr] + bias, rope cols>=1024
        GArgs a{};
        a.A0 = Xb; a.B0 = Wc1; a.B0r2 = Wc1 + 2l * 1048576; a.K0 = 2048;
        a.bias = biasD; a.C = ckk; a.C2 = ckk + 1024;
        a.colSplit = 1024; a.innerCnt = 1; a.scale = 1.f;
        gemm_mfma<2048, 2048, 1536, 1536, FLAG_ROPE2, 0, 0>
            <<<dim3(12, 32, 1), blk, 0, stream>>>(a);
    }
    {   // up-proj q: [q_c | q_r(rope)] = c_q @ [Wuq|Wqr] + bias
        GArgs a{};
        a.A0 = ckk; a.B0 = Wc2; a.B0r2 = Wqr_t; a.K0 = 512;
        a.bias = biasQ; a.C = q_c; a.C2 = q_r;
        a.colSplit = 2048; a.innerCnt = 1; a.scale = 1.f;
        gemm_mfma<1536, 512, 2048, 8192, FLAG_ROPE2, 0, 0>
            <<<dim3(80, 32, 1), blk, 0, stream>>>(a);
    }
    {   // up-proj kv: [k_c | v^T] = c_kv @ [Wuk|Wuv] + bias
        GArgs a{};
        a.A0 = ckk + 512; a.B0 = Wc2 + 1048576; a.B0r2 = Wc2 + 2l * 1048576;
        a.K0 = 512;
        a.bias = biasK; a.C = k_c; a.C2 = v_t;
        a.colSplit = 2048; a.innerCnt = 1; a.scale = 1.f;
        gemm_mfma<1536, 512, 2048, 4096, FLAG_TRANS2, 0, 0>
            <<<dim3(32, 32, 1), blk, 0, stream>>>(a);
    }

    // ---- attention, two batch-halves (attn = 64 slices of raw scaled scores) ----
    for (int half = 0; half < 2; ++half) {
        long b0 = half * 4;
        {   // scores: qc.kc^T (K=128) + qr.kr^T (K=512), scaled (k_r = ckk+1024)
            GArgs a{};
            a.A0 = q_c + b0 * 1048576; a.sA0o = 1048576; a.sA0i = 128; a.K0 = 128;
            a.B0 = k_c + b0 * 1048576; a.sB0o = 1048576; a.sB0i = 128;
            a.B0r2 = a.B0;
            a.A1 = q_r + b0 * 4194304; a.sA1o = 4194304; a.sA1i = 512; a.K1 = 512;
            a.B1 = ckk + 1024 + b0 * 786432; a.sB1o = 786432; a.sB1i = 0;
            a.C = attn; a.C2 = attn; a.sCo = 16l * 262144; a.sCi = 262144;
            a.colSplit = NOSPLIT; a.innerCnt = 16;
            a.scale = 1.0f / 33.941125496954285f;   // 1/(sqrt(128)+sqrt(512))
            gemm_mfma<2048, 2048, 512, 1, FLAG_SCALE, 8192, 1536>
                <<<dim3(4, 4, 64), blk, 0, stream>>>(a);
        }
        // fused softmax + PV -> o
        pv_soft<<<dim3(16, 64, 1), blk, 0, stream>>>(attn, v_t, o, (int)b0);
    }

    // ---- final projection (fp32 out) ----
    {
        GArgs a{};
        a.A0 = o; a.B0 = Wfc_t; a.B0r2 = Wfc_t; a.K0 = 2048;
        a.bias = bfc; a.C = out; a.C2 = out;
        a.colSplit = NOSPLIT; a.innerCnt = 1; a.scale = 1.f;
        gemm_mfma<2048, 2048, 2048, 1, FLAG_F32OUT, 0, 0>
            <<<dim3(16, 32, 1), blk, 0, stream>>>(a);
    }
}

// Round 6
// 478.310 us; speedup vs baseline: 5.1415x; 1.0064x over previous
//
#include <hip/hip_runtime.h>
#include <hip/hip_bf16.h>
#include <stdint.h>

typedef unsigned short u16;
typedef short bf16x8 __attribute__((ext_vector_type(8)));
typedef float f32x4 __attribute__((ext_vector_type(4)));

__device__ __forceinline__ float us2f(u16 u) {
    union { unsigned int i; float f; } x;
    x.i = ((unsigned int)u) << 16;
    return x.f;
}

__device__ __forceinline__ u16 f2us(float f) {
    union { float f; unsigned int i; } x; x.f = f;
    unsigned int lsb = (x.i >> 16) & 1u;
    x.i += 0x7FFFu + lsb;            // round-to-nearest-even
    return (u16)(x.i >> 16);
}

// async global->LDS, 16B per lane. LDS dest = wave-uniform base + lane*16.
__device__ __forceinline__ void gl_lds16(const u16* g, u16* l) {
    __builtin_amdgcn_global_load_lds(
        (const __attribute__((address_space(1))) void*)(uintptr_t)(const void*)g,
        (__attribute__((address_space(3))) void*)(uintptr_t)(void*)l,
        16, 0, 0);
}

#define FLAG_ROPE2  1   // region2 cols get interleaved RoPE (head_dim 512)
#define FLAG_TRANS2 4   // region2 written transposed (LDC2 = rows stride)
#define FLAG_F32OUT 8   // region1 written fp32

struct GArgs {
    const u16 *A0, *B0, *B0r2;
    int K0;
    const float* bias;          // indexed by global col (concatenated)
    void* C; void* C2;
    int colSplit;               // cols >= colSplit -> region2 (multiple of 128)
};

// ---------------------------------------------------------------------------
// NT MFMA GEMM: C[m,n] = sum_k A[m,k]*Bt[n,k]. 128x128 tile, BK=64,
// 256 threads = 4 waves 2x2, each wave 64x64 (4x4 MFMA subtiles).
// bf16 in (K-major both sides), fp32 accum. Column-split epilogue: cols >=
// colSplit go to C2 (optionally RoPE'd or transposed), B rows from B0r2.
// LDS rotation: slot s of row r holds chunk (s - r) & 7 (measured 0 confl).
// ---------------------------------------------------------------------------
template <int LDA0, int LDB0, int LDC, int LDC2, int FLAGS>
__global__ __launch_bounds__(256)
void gemm_mfma(GArgs g)
{
    __shared__ u16 As[128 * 64];   // 16 KB
    __shared__ u16 Bs[128 * 64];   // 16 KB

    const int t    = threadIdx.x;
    const int lane = t & 63;
    const int w    = t >> 6;
    const int wm   = w >> 1, wn = w & 1;
    const int m0   = blockIdx.y * 128;
    const int n0   = blockIdx.x * 128;
    const bool r2  = (n0 >= g.colSplit);

    const int srow = t >> 3;    // 0..31 base row for staging
    const int sp   = t & 7;     // LDS slot within row
    u16* dA = As + t * 8;
    u16* dB = Bs + t * 8;

    const int lr = lane & 15;
    const int jj = lane >> 4;

    f32x4 acc[4][4];
#pragma unroll
    for (int i = 0; i < 4; ++i)
#pragma unroll
        for (int j = 0; j < 4; ++j)
            acc[i][j] = (f32x4){0.f, 0.f, 0.f, 0.f};

    {
        const u16* A = g.A0;
        const u16* B = r2 ? g.B0r2 - (long)g.colSplit * LDB0 : g.B0;
        const u16* gA[4];
        const u16* gB[4];
#pragma unroll
        for (int r = 0; r < 4; ++r) {
            int row = r * 32 + srow;
            int gc  = (sp - row) & 7;
            gA[r] = A + (long)(m0 + row) * LDA0 + gc * 8;
            gB[r] = B + (long)(n0 + row) * LDB0 + gc * 8;
        }
        for (int kt = 0; kt < g.K0; kt += 64) {
#pragma unroll
            for (int r = 0; r < 4; ++r) {
                gl_lds16(gA[r], dA + r * 2048);
                gl_lds16(gB[r], dB + r * 2048);
                gA[r] += 64; gB[r] += 64;
            }
            __syncthreads();
#pragma unroll
            for (int s = 0; s < 2; ++s) {
                bf16x8 af[4], bfr[4];
#pragma unroll
                for (int mi = 0; mi < 4; ++mi) {
                    int row  = wm * 64 + mi * 16 + lr;
                    int slot = (s * 4 + jj + row) & 7;
                    af[mi] = *(const bf16x8*)&As[row * 64 + slot * 8];
                }
#pragma unroll
                for (int ni = 0; ni < 4; ++ni) {
                    int row  = wn * 64 + ni * 16 + lr;
                    int slot = (s * 4 + jj + row) & 7;
                    bfr[ni] = *(const bf16x8*)&Bs[row * 64 + slot * 8];
                }
#pragma unroll
                for (int mi = 0; mi < 4; ++mi)
#pragma unroll
                    for (int ni = 0; ni < 4; ++ni)
                        acc[mi][ni] = __builtin_amdgcn_mfma_f32_16x16x32_bf16(
                            af[mi], bfr[ni], acc[mi][ni], 0, 0, 0);
            }
            __syncthreads();
        }
    }

    // epilogue. C/D layout: col = lane&15, row = (lane>>4)*4 + reg.
    const int eCol0 = n0 + wn * 64 + lr;
    const int eRow0 = m0 + wm * 64 + jj * 4;
    const bool oddc = lane & 1;

    if (g.bias) {
#pragma unroll
        for (int ni = 0; ni < 4; ++ni) {
            float bv = g.bias[eCol0 + ni * 16];
#pragma unroll
            for (int mi = 0; mi < 4; ++mi) {
                acc[mi][ni][0] += bv; acc[mi][ni][1] += bv;
                acc[mi][ni][2] += bv; acc[mi][ni][3] += bv;
            }
        }
    }

    if (!r2) {
#pragma unroll
        for (int mi = 0; mi < 4; ++mi)
#pragma unroll
            for (int ni = 0; ni < 4; ++ni) {
                int rowb = eRow0 + mi * 16;
                int colg = eCol0 + ni * 16;
                if (FLAGS & FLAG_F32OUT) {
                    float* cp = (float*)g.C;
#pragma unroll
                    for (int i = 0; i < 4; ++i)
                        cp[(long)(rowb + i) * LDC + colg] = acc[mi][ni][i];
                } else {
                    u16* cp = (u16*)g.C;
#pragma unroll
                    for (int i = 0; i < 4; ++i)
                        cp[(long)(rowb + i) * LDC + colg] = f2us(acc[mi][ni][i]);
                }
            }
    } else if (FLAGS & FLAG_ROPE2) {
        // incremental-rotation RoPE: per ni only 3 sincos; rows within a
        // block never wrap mod 512 (m0%512 in {0,128,256,384}).
        const float base_s = (float)(eRow0 & 511);
#pragma unroll
        for (int ni = 0; ni < 4; ++ni) {
            int col2 = eCol0 + ni * 16 - g.colSplit;
            int rp   = (col2 & 511) & ~1;
            float f  = __expf(-9.2103403719761836f * (float)rp * (1.0f / 512.0f));
            float s1, c1, s16, c16, sb, cb;
            __sincosf(f, &s1, &c1);
            __sincosf(16.0f * f, &s16, &c16);
            __sincosf(base_s * f, &sb, &cb);
            float cm = cb, sm = sb;          // angle at row eRow0 + mi*16
#pragma unroll
            for (int mi = 0; mi < 4; ++mi) {
                f32x4 v = acc[mi][ni];
                float cr = cm, sr = sm;      // angle at current row
#pragma unroll
                for (int i = 0; i < 4; ++i) {
                    float other = __shfl_xor(v[i], 1, 64);
                    v[i] = oddc ? (v[i] * cr + other * sr)
                                : (v[i] * cr - other * sr);
                    float cn = cr * c1 - sr * s1;   // step +1 row
                    sr = sr * c1 + cr * s1; cr = cn;
                }
                int rowb = eRow0 + mi * 16;
                u16* cp = (u16*)g.C2;
#pragma unroll
                for (int i = 0; i < 4; ++i)
                    cp[(long)(rowb + i) * LDC2 + col2] = f2us(v[i]);
                float cn = cm * c16 - sm * s16;     // step +16 rows
                sm = sm * c16 + cm * s16; cm = cn;
            }
        }
    } else {
#pragma unroll
        for (int mi = 0; mi < 4; ++mi)
#pragma unroll
            for (int ni = 0; ni < 4; ++ni) {
                int rowb = eRow0 + mi * 16;
                int col2 = eCol0 + ni * 16 - g.colSplit;
                if (FLAGS & FLAG_TRANS2) {
                    u16* cp = (u16*)g.C2 + (long)col2 * LDC2 + rowb;
                    ushort4 o4;
                    o4.x = f2us(acc[mi][ni][0]); o4.y = f2us(acc[mi][ni][1]);
                    o4.z = f2us(acc[mi][ni][2]); o4.w = f2us(acc[mi][ni][3]);
                    *(ushort4*)cp = o4;
                } else {
                    u16* cp = (u16*)g.C2;
#pragma unroll
                    for (int i = 0; i < 4; ++i)
                        cp[(long)(rowb + i) * LDC2 + col2] = f2us(acc[mi][ni][i]);
                }
            }
    }
}

// ---------------------------------------------------------------------------
// Fused attention: per block = (b, h, 128 q-rows). Loops 4 key-tiles of 128:
//   S = qc.kc^T (K=128) + qr.kr^T (K=512)   [BK=32 staged, MFMA]
//   P = exp(S*scale)  (C=0: |S|<~2 measured-safe)  -> LDS (stride 136)
//   l_sum[row] += row-sums (LDS atomics)
//   O += P.V  (V = v_t rows, K-major)
// Epilogue: O / l_sum -> o[bs][h*128+vcol].   No attn matrix in HBM.
// ---------------------------------------------------------------------------
__global__ __launch_bounds__(256, 2)
void attn_fused(const u16* __restrict__ qc, const u16* __restrict__ kc,
                const u16* __restrict__ qr, const u16* __restrict__ kr,
                const u16* __restrict__ vt, u16* __restrict__ o)
{
    __shared__ u16 As[128 * 32];       // 8 KB  (BK=32)
    __shared__ u16 Bs[128 * 32];       // 8 KB
    __shared__ u16 Ps[128 * 136];      // 34 KB (pad 128->136 for banks)
    __shared__ float l_sum[128];

    const int t    = threadIdx.x;
    const int lane = t & 63;
    const int w    = t >> 6;
    const int wm   = w >> 1, wn = w & 1;
    const int m0   = blockIdx.x * 128;
    const int z    = blockIdx.y;           // 0..127
    const int bb   = z >> 4, h = z & 15;

    if (t < 128) l_sum[t] = 0.f;

    // staging: 2 chunks/thread: rows t>>2 and 64+(t>>2), slot t&3,
    // rotation gc = (slot - (row>>1)) & 3  (8-position spread per 16 lanes).
    const int srow = t >> 2;
    const int sp   = t & 3;
    u16* dA = As + t * 8;
    u16* dB = Bs + t * 8;
    int rrow[2], rgc[2];
#pragma unroll
    for (int r = 0; r < 2; ++r) {
        rrow[r] = r * 64 + srow;
        rgc[r]  = (sp - (rrow[r] >> 1)) & 3;
    }

    const int lr = lane & 15;
    const int jj = lane >> 4;

    // persistent A (q) staging pointers
    const u16* gqc[2];
    const u16* gqr[2];
#pragma unroll
    for (int r = 0; r < 2; ++r) {
        gqc[r] = qc + (long)(bb * 512 + m0 + rrow[r]) * 2048 + h * 128 + rgc[r] * 8;
        gqr[r] = qr + (long)(bb * 512 + m0 + rrow[r]) * 8192 + h * 512 + rgc[r] * 8;
    }

    f32x4 acc_o[4][4];
#pragma unroll
    for (int i = 0; i < 4; ++i)
#pragma unroll
        for (int j = 0; j < 4; ++j) acc_o[i][j] = (f32x4){0.f, 0.f, 0.f, 0.f};

    const float scale = 1.0f / 33.941125496954285f;   // 1/(sqrt(128)+sqrt(512))

    for (int nt = 0; nt < 4; ++nt) {
        const int n0k = nt * 128;

        f32x4 acc_s[4][4];
#pragma unroll
        for (int i = 0; i < 4; ++i)
#pragma unroll
            for (int j = 0; j < 4; ++j) acc_s[i][j] = (f32x4){0.f, 0.f, 0.f, 0.f};

        // ---- S = qc.kc^T + qr.kr^T over this key tile ----
        const u16* pa[2];
        const u16* pb[2];
#pragma unroll
        for (int r = 0; r < 2; ++r) {
            pa[r] = gqc[r];
            pb[r] = kc + (long)(bb * 512 + n0k + rrow[r]) * 2048 + h * 128 + rgc[r] * 8;
        }
        for (int seg = 0; seg < 2; ++seg) {
            int iters = seg == 0 ? 4 : 16;
            for (int kt = 0; kt < iters; ++kt) {
#pragma unroll
                for (int r = 0; r < 2; ++r) {
                    gl_lds16(pa[r], dA + r * 2048);
                    gl_lds16(pb[r], dB + r * 2048);
                    pa[r] += 32; pb[r] += 32;
                }
                __syncthreads();
                bf16x8 af[4], bfr[4];
#pragma unroll
                for (int mi = 0; mi < 4; ++mi) {
                    int row  = wm * 64 + mi * 16 + lr;
                    int slot = (jj + (row >> 1)) & 3;
                    af[mi] = *(const bf16x8*)&As[row * 32 + slot * 8];
                }
#pragma unroll
                for (int ni = 0; ni < 4; ++ni) {
                    int row  = wn * 64 + ni * 16 + lr;
                    int slot = (jj + (row >> 1)) & 3;
                    bfr[ni] = *(const bf16x8*)&Bs[row * 32 + slot * 8];
                }
#pragma unroll
                for (int mi = 0; mi < 4; ++mi)
#pragma unroll
                    for (int ni = 0; ni < 4; ++ni)
                        acc_s[mi][ni] = __builtin_amdgcn_mfma_f32_16x16x32_bf16(
                            af[mi], bfr[ni], acc_s[mi][ni], 0, 0, 0);
                __syncthreads();
            }
            if (seg == 0) {
#pragma unroll
                for (int r = 0; r < 2; ++r) {
                    pa[r] = gqr[r];
                    pb[r] = kr + (long)(bb * 512 + n0k + rrow[r]) * 1536 + rgc[r] * 8;
                }
            }
        }

        // ---- P = exp(S*scale) -> Ps; l partial sums -> l_sum ----
#pragma unroll
        for (int mi = 0; mi < 4; ++mi) {
            float rowpart[4] = {0.f, 0.f, 0.f, 0.f};
#pragma unroll
            for (int ni = 0; ni < 4; ++ni) {
                f32x4 v = acc_s[mi][ni];
                int colP = wn * 64 + ni * 16 + lr;
#pragma unroll
                for (int i = 0; i < 4; ++i) {
                    float e = __expf(v[i] * scale);
                    rowpart[i] += e;
                    int rowP = wm * 64 + mi * 16 + jj * 4 + i;
                    Ps[rowP * 136 + colP] = f2us(e);
                }
            }
#pragma unroll
            for (int i = 0; i < 4; ++i) {
                float s4 = rowpart[i];
                s4 += __shfl_xor(s4, 1, 64);
                s4 += __shfl_xor(s4, 2, 64);
                s4 += __shfl_xor(s4, 4, 64);
                s4 += __shfl_xor(s4, 8, 64);
                if ((lane & 15) == 0)
                    atomicAdd(&l_sum[wm * 64 + mi * 16 + jj * 4 + i], s4);
            }
        }

        // ---- O += P.V  (V staged into Bs, 4 iters of 32 keys) ----
        const u16* pv[2];
#pragma unroll
        for (int r = 0; r < 2; ++r)
            pv[r] = vt + (long)(h * 128 + rrow[r]) * 4096 + bb * 512 + n0k + rgc[r] * 8;
        for (int kt = 0; kt < 4; ++kt) {
#pragma unroll
            for (int r = 0; r < 2; ++r) {
                gl_lds16(pv[r], dB + r * 2048);
                pv[r] += 32;
            }
            __syncthreads();
            bf16x8 af[4], bfr[4];
#pragma unroll
            for (int mi = 0; mi < 4; ++mi) {
                int row = wm * 64 + mi * 16 + lr;
                af[mi] = *(const bf16x8*)&Ps[row * 136 + (kt * 4 + jj) * 8];
            }
#pragma unroll
            for (int ni = 0; ni < 4; ++ni) {
                int row  = wn * 64 + ni * 16 + lr;
                int slot = (jj + (row >> 1)) & 3;
                bfr[ni] = *(const bf16x8*)&Bs[row * 32 + slot * 8];
            }
#pragma unroll
            for (int mi = 0; mi < 4; ++mi)
#pragma unroll
                for (int ni = 0; ni < 4; ++ni)
                    acc_o[mi][ni] = __builtin_amdgcn_mfma_f32_16x16x32_bf16(
                        af[mi], bfr[ni], acc_o[mi][ni], 0, 0, 0);
            __syncthreads();
        }
    }

    // ---- epilogue: O / l, write o[bs][h*128 + vcol] ----
#pragma unroll
    for (int mi = 0; mi < 4; ++mi) {
#pragma unroll
        for (int i = 0; i < 4; ++i) {
            int row = wm * 64 + mi * 16 + jj * 4 + i;
            float linv = 1.0f / l_sum[row];
            long grow = (long)(bb * 512 + m0 + row) * 2048 + h * 128;
#pragma unroll
            for (int ni = 0; ni < 4; ++ni) {
                int colc = wn * 64 + ni * 16 + lr;
                o[grow + colc] = f2us(acc_o[mi][ni][i] * linv);
            }
        }
    }
}

// ---------------------------------------------------------------------------
// fp32 -> bf16 elementwise (vectorized x4)
// ---------------------------------------------------------------------------
__global__ __launch_bounds__(256)
void conv_f32_bf16(const float* __restrict__ in, u16* __restrict__ out)
{
    int i = blockIdx.x * 256 + threadIdx.x;
    float4 v = ((const float4*)in)[i];
    ushort4 o;
    o.x = f2us(v.x); o.y = f2us(v.y); o.z = f2us(v.z); o.w = f2us(v.w);
    ((ushort4*)out)[i] = o;
}

// ---------------------------------------------------------------------------
// batched fp32 [K][N] -> bf16 [N][K] transpose-convert, 32x32 LDS tile
// ---------------------------------------------------------------------------
struct TC3 { const float* in0; const float* in1; const float* in2;
             u16* out; long outStride; int K; int N; };

__global__ __launch_bounds__(256)
void tconv3(TC3 a)
{
    __shared__ float tile[32][33];
    const float* in = blockIdx.z == 0 ? a.in0 : (blockIdx.z == 1 ? a.in1 : a.in2);
    u16* out = a.out + blockIdx.z * a.outStride;
    int n0 = blockIdx.x * 32, k0 = blockIdx.y * 32;
    int c = threadIdx.x & 31, r0 = threadIdx.x >> 5;
#pragma unroll
    for (int j = 0; j < 4; ++j) {
        int r = r0 + j * 8;
        tile[r][c] = in[(long)(k0 + r) * a.N + n0 + c];
    }
    __syncthreads();
#pragma unroll
    for (int j = 0; j < 4; ++j) {
        int r = r0 + j * 8;
        out[(long)(n0 + r) * a.K + k0 + c] = f2us(tile[c][r]);
    }
}

// ---------------------------------------------------------------------------
extern "C" void kernel_launch(void* const* d_in, const int* in_sizes, int n_in,
                              void* d_out, int out_size, void* d_ws, size_t ws_size,
                              hipStream_t stream)
{
    (void)in_sizes; (void)n_in; (void)out_size; (void)ws_size;

    const float* X    = (const float*)d_in[0];
    const float* Wdq  = (const float*)d_in[1];  const float* bdq  = (const float*)d_in[2];
    const float* Wdkv = (const float*)d_in[3];  const float* bdkv = (const float*)d_in[4];
    const float* Wuq  = (const float*)d_in[5];  const float* buq  = (const float*)d_in[6];
    const float* Wuk  = (const float*)d_in[7];  const float* buk  = (const float*)d_in[8];
    const float* Wuv  = (const float*)d_in[9];  const float* buv  = (const float*)d_in[10];
    const float* Wqr  = (const float*)d_in[11]; const float* bqr  = (const float*)d_in[12];
    const float* Wkr  = (const float*)d_in[13]; const float* bkr  = (const float*)d_in[14];
    const float* Wfc  = (const float*)d_in[15]; const float* bfc  = (const float*)d_in[16];
    float* out = (float*)d_out;

    // workspace (u16 elems), ~184 MB + small fp32 bias tail. No attn buffer.
    u16* ws = (u16*)d_ws;
    u16* Xb     = ws;                 // [4096][2048]               8M
    u16* Wc1    = Xb   + 8388608;     // [Wdq_t|Wdkv_t|Wkr_t] = [1536][2048]  3M
    u16* Wc2    = Wc1  + 3145728;     // [Wuq_t|Wuk_t|Wuv_t]  = [6144][512]   3M
    u16* Wqr_t  = Wc2  + 3145728;     // [8192][512]                4M
    u16* Wfc_t  = Wqr_t + 4194304;    // [2048][2048]               4M
    u16* ckk    = Wfc_t + 4194304;    // [4096][1536] = c_q|c_kv|k_r  6M
    u16* q_c    = ckk  + 6291456;     // [4096][2048]               8M
    u16* k_c    = q_c  + 8388608;     // [4096][2048]               8M
    u16* v_t    = k_c  + 8388608;     // [2048][4096] (V^T)         8M
    u16* q_r    = v_t  + 8388608;     // [4096][8192]               32M
    u16* o      = q_r  + 33554432;    // [4096][2048]               8M
    float* biasD = (float*)(o + 8388608);   // 1536
    float* biasQ = biasD + 1536;            // 10240
    float* biasK = biasQ + 10240;           // 4096

    dim3 blk(256, 1, 1);

    // ---- converts (5 dispatches) + bias concats (async d2d copies) ----
    conv_f32_bf16<<<8192, blk, 0, stream>>>(X, Xb);
    {   TC3 a{Wdq, Wdkv, Wkr, Wc1, 1048576, 2048, 512};
        tconv3<<<dim3(16, 64, 3), blk, 0, stream>>>(a); }
    {   TC3 a{Wuq, Wuk, Wuv, Wc2, 1048576, 512, 2048};
        tconv3<<<dim3(64, 16, 3), blk, 0, stream>>>(a); }
    {   TC3 a{Wqr, nullptr, nullptr, Wqr_t, 0, 512, 8192};
        tconv3<<<dim3(256, 16, 1), blk, 0, stream>>>(a); }
    {   TC3 a{Wfc, nullptr, nullptr, Wfc_t, 0, 2048, 2048};
        tconv3<<<dim3(64, 64, 1), blk, 0, stream>>>(a); }
    hipMemcpyAsync(biasD,        bdq,  512 * 4,  hipMemcpyDeviceToDevice, stream);
    hipMemcpyAsync(biasD + 512,  bdkv, 512 * 4,  hipMemcpyDeviceToDevice, stream);
    hipMemcpyAsync(biasD + 1024, bkr,  512 * 4,  hipMemcpyDeviceToDevice, stream);
    hipMemcpyAsync(biasQ,        buq,  2048 * 4, hipMemcpyDeviceToDevice, stream);
    hipMemcpyAsync(biasQ + 2048, bqr,  8192 * 4, hipMemcpyDeviceToDevice, stream);
    hipMemcpyAsync(biasK,        buk,  2048 * 4, hipMemcpyDeviceToDevice, stream);
    hipMemcpyAsync(biasK + 2048, buv,  2048 * 4, hipMemcpyDeviceToDevice, stream);

    const int NOSPLIT = 1 << 30;

    {   // down-proj: ckk[4096][1536] = X @ [Wdq|Wdkv|Wkr] + bias, rope cols>=1024
        GArgs a{};
        a.A0 = Xb; a.B0 = Wc1; a.B0r2 = Wc1 + 2l * 1048576; a.K0 = 2048;
        a.bias = biasD; a.C = ckk; a.C2 = ckk + 1024;
        a.colSplit = 1024;
        gemm_mfma<2048, 2048, 1536, 1536, FLAG_ROPE2>
            <<<dim3(12, 32, 1), blk, 0, stream>>>(a);
    }
    {   // up-proj q: [q_c | q_r(rope)] = c_q @ [Wuq|Wqr] + bias
        GArgs a{};
        a.A0 = ckk; a.B0 = Wc2; a.B0r2 = Wqr_t; a.K0 = 512;
        a.bias = biasQ; a.C = q_c; a.C2 = q_r;
        a.colSplit = 2048;
        gemm_mfma<1536, 512, 2048, 8192, FLAG_ROPE2>
            <<<dim3(80, 32, 1), blk, 0, stream>>>(a);
    }
    {   // up-proj kv: [k_c | v^T] = c_kv @ [Wuk|Wuv] + bias
        GArgs a{};
        a.A0 = ckk + 512; a.B0 = Wc2 + 1048576; a.B0r2 = Wc2 + 2l * 1048576;
        a.K0 = 512;
        a.bias = biasK; a.C = k_c; a.C2 = v_t;
        a.colSplit = 2048;
        gemm_mfma<1536, 512, 2048, 4096, FLAG_TRANS2>
            <<<dim3(32, 32, 1), blk, 0, stream>>>(a);
    }

    // ---- fused attention: scores + softmax(C=0) + PV, no attn buffer ----
    attn_fused<<<dim3(4, 128, 1), blk, 0, stream>>>(
        q_c, k_c, q_r, ckk + 1024, v_t, o);

    // ---- final projection (fp32 out) ----
    {
        GArgs a{};
        a.A0 = o; a.B0 = Wfc_t; a.B0r2 = Wfc_t; a.K0 = 2048;
        a.bias = bfc; a.C = out; a.C2 = out;
        a.colSplit = NOSPLIT;
        gemm_mfma<2048, 2048, 2048, 1, FLAG_F32OUT>
            <<<dim3(16, 32, 1), blk, 0, stream>>>(a);
    }
}